// Round 1
// 748.381 us; speedup vs baseline: 1.2804x; 1.2804x over previous
//
#include <hip/hip_runtime.h>

#define NN 100000   // nodes
#define NC 200000   // cells
#define NE 300000   // edges
#define D  128

typedef unsigned short u16;
typedef __attribute__((ext_vector_type(8))) short bf16x8;  // 8 bf16 = 4 VGPRs
typedef __attribute__((ext_vector_type(4))) float f32x4;   // MFMA accumulator

__device__ __forceinline__ u16 f2bf(float x) {            // fp32 -> bf16 (RNE)
    unsigned int u = __float_as_uint(x);
    u += 0x7fffu + ((u >> 16) & 1u);
    return (u16)(u >> 16);
}
__device__ __forceinline__ float bf2f(u16 h) {
    return __uint_as_float((unsigned int)h << 16);
}

#define MFMA16(a, b, c) __builtin_amdgcn_mfma_f32_16x16x32_bf16((a), (b), (c), 0, 0, 0)

// ---------------- attention logits + softmax denominator ----------------
__global__ __launch_bounds__(256) void k_att(const float* __restrict__ edge_attr,
                                             const float* __restrict__ emb,
                                             const int* __restrict__ ei,
                                             float* __restrict__ expv,
                                             float* __restrict__ denom) {
    int e = blockIdx.x * 4 + (threadIdx.x >> 6);
    int lane = threadIdx.x & 63;
    if (e >= NE) return;
    int send = ei[e];          // edge_index[0]
    int recv = ei[NE + e];     // edge_index[1]
    float2 a = ((const float2*)(edge_attr + (size_t)e * D))[lane];
    float2 r = ((const float2*)(emb + (size_t)recv * D))[lane];
    float2 s = ((const float2*)(emb + (size_t)send * D))[lane];
    float dr = a.x * r.x + a.y * r.y;
    float ds = a.x * s.x + a.y * s.y;
    #pragma unroll
    for (int off = 32; off > 0; off >>= 1) {
        dr += __shfl_xor(dr, off);
        ds += __shfl_xor(ds, off);
    }
    if (lane == 0) {
        const float inv_scale = 0.08838834764831845f; // 1/sqrt(128)
        float er = __expf(dr * inv_scale);
        float es = __expf(ds * inv_scale);
        expv[e] = er;
        expv[NE + e] = es;
        atomicAdd(&denom[recv], er);
        atomicAdd(&denom[send], es);
    }
}

// ---------------- CSR build: histogram / scan / fill ----------------
__global__ __launch_bounds__(256) void k_hist_att(const int* __restrict__ ei,
                                                  int* __restrict__ cnt) {
    int i = blockIdx.x * 256 + threadIdx.x;
    if (i >= 2 * NE) return;
    int t = (i < NE) ? ei[NE + i] : ei[i - NE];
    atomicAdd(&cnt[t], 1);
}

__global__ __launch_bounds__(256) void k_hist_face(const int* __restrict__ face,
                                                   int* __restrict__ cnt) {
    int i = blockIdx.x * 256 + threadIdx.x;
    if (i >= 3 * NC) return;
    atomicAdd(&cnt[face[i]], 1);
}

__global__ __launch_bounds__(256) void k_scan_blocks(const int* __restrict__ cnt,
                                                     int* __restrict__ bsum) {
    __shared__ int s[256];
    int t = threadIdx.x;
    int i = blockIdx.x * 256 + t;
    s[t] = (i < NN) ? cnt[i] : 0;
    __syncthreads();
    #pragma unroll
    for (int off = 128; off > 0; off >>= 1) {
        if (t < off) s[t] += s[t + off];
        __syncthreads();
    }
    if (t == 0) bsum[blockIdx.x] = s[0];
}

__global__ __launch_bounds__(512) void k_scan_top(int* __restrict__ bsum, int nb) {
    __shared__ int s[512];
    int t = threadIdx.x;
    int v = (t < nb) ? bsum[t] : 0;
    s[t] = v;
    __syncthreads();
    #pragma unroll
    for (int off = 1; off < 512; off <<= 1) {
        int x = (t >= off) ? s[t - off] : 0;
        __syncthreads();
        s[t] += x;
        __syncthreads();
    }
    if (t < nb) bsum[t] = s[t] - v;   // exclusive
}

__global__ __launch_bounds__(256) void k_scan_final(const int* __restrict__ cnt,
                                                    const int* __restrict__ bsum,
                                                    int* __restrict__ off_out,
                                                    int total) {
    __shared__ int s[256];
    int t = threadIdx.x;
    int i = blockIdx.x * 256 + t;
    int v = (i < NN) ? cnt[i] : 0;
    s[t] = v;
    __syncthreads();
    #pragma unroll
    for (int off = 1; off < 256; off <<= 1) {
        int x = (t >= off) ? s[t - off] : 0;
        __syncthreads();
        s[t] += x;
        __syncthreads();
    }
    if (i < NN) off_out[i] = s[t] - v + bsum[blockIdx.x];
    if (i == 0) off_out[NN] = total;
}

__global__ __launch_bounds__(256) void k_fill_att(const int* __restrict__ ei,
                                                  const int* __restrict__ offs,
                                                  int* __restrict__ cur,
                                                  int* __restrict__ slots) {
    int i = blockIdx.x * 256 + threadIdx.x;
    if (i >= 2 * NE) return;
    int t = (i < NE) ? ei[NE + i] : ei[i - NE];
    int pos = offs[t] + atomicAdd(&cur[t], 1);
    slots[pos] = i;
}

__global__ __launch_bounds__(256) void k_fill_face(const int* __restrict__ face,
                                                   const int* __restrict__ offs,
                                                   int* __restrict__ cur,
                                                   int* __restrict__ slots) {
    int i = blockIdx.x * 256 + threadIdx.x;
    if (i >= 3 * NC) return;
    int t = face[i];
    int pos = offs[t] + atomicAdd(&cur[t], 1);
    int c = i; if (c >= NC) c -= NC; if (c >= NC) c -= NC;   // cell id = i mod NC
    slots[pos] = c;
}

// ---------------- gather-style node aggregation (no atomics) ----------------
__global__ __launch_bounds__(256) void k_agg_gather(const float* __restrict__ edge_attr,
                                                    const float* __restrict__ expv,
                                                    const float* __restrict__ denom,
                                                    const int* __restrict__ offs,
                                                    const int* __restrict__ slots,
                                                    float* __restrict__ na) {
    int n = blockIdx.x * 4 + (threadIdx.x >> 6);
    int lane = threadIdx.x & 63;
    if (n >= NN) return;
    int s0 = offs[n], s1 = offs[n + 1];
    float2 acc = {0.f, 0.f};
    for (int s = s0; s < s1; ++s) {
        int eid = slots[s];                       // in [0, 2E)
        int row = (eid < NE) ? eid : eid - NE;
        float w = expv[eid];
        float2 a = ((const float2*)(edge_attr + (size_t)row * D))[lane];
        acc.x += w * a.x;
        acc.y += w * a.y;
    }
    float inv = (s1 > s0) ? 1.f / denom[n] : 0.f;
    float2* p = (float2*)(na + (size_t)n * D) + lane;
    float2 r; r.x = acc.x * inv; r.y = acc.y * inv;
    *p = r;
}

// ---------------- gather-style scatter-mean (no atomics) ----------------
__global__ __launch_bounds__(256) void k_smean_gather(const float* __restrict__ cell_out,
                                                      const int* __restrict__ offs,
                                                      const int* __restrict__ slots,
                                                      float* __restrict__ node_out) {
    int n = blockIdx.x * 4 + (threadIdx.x >> 6);
    int lane = threadIdx.x & 63;
    if (n >= NN) return;
    int s0 = offs[n], s1 = offs[n + 1];
    float2 acc = {0.f, 0.f};
    for (int s = s0; s < s1; ++s) {
        int c = slots[s];                         // cell id
        float2 y = ((const float2*)(cell_out + (size_t)c * D))[lane];
        acc.x += y.x;
        acc.y += y.y;
    }
    int deg = s1 - s0;
    float inv = deg ? 1.f / (float)deg : 0.f;
    float2* p = (float2*)(node_out + (size_t)n * D) + lane;
    float2 r; r.x = acc.x * inv; r.y = acc.y * inv;
    *p = r;
}

// ---------------- W prepack: fragment-major bf16 hi/lo split ----------------
// Fragment f = kt*8 + nt. Lane l, elem i holds W[kt*32 + 8*(l>>4) + i][nt*16 + (l&15)].
// Stored at w?h[f*512 + l*8 + i] so a wave loads one fragment with a coalesced 1 KB read.
__global__ __launch_bounds__(256) void k_wsplit(const float* __restrict__ W1,
                                                const float* __restrict__ W2,
                                                u16* __restrict__ w1h, u16* __restrict__ w1l,
                                                u16* __restrict__ w2h, u16* __restrict__ w2l) {
    int tid = blockIdx.x * 256 + threadIdx.x;
    if (tid >= 6144) return;                 // 64 W1 frags + 32 W2 frags, 64 lanes each
    int l = tid & 63;
    int f = tid >> 6;
    const float* W; u16 *oh, *ol; int fi;
    if (f < 64) { W = W1; oh = w1h; ol = w1l; fi = f; }
    else        { W = W2; oh = w2h; ol = w2l; fi = f - 64; }
    int kt = fi >> 3, nt = fi & 7;
    int k0 = kt * 32 + 8 * (l >> 4);
    int n  = nt * 16 + (l & 15);
    #pragma unroll
    for (int i = 0; i < 8; i++) {
        float x = W[(size_t)(k0 + i) * 128 + n];
        u16 h = f2bf(x);
        oh[(size_t)fi * 512 + l * 8 + i] = h;
        ol[(size_t)fi * 512 + l * 8 + i] = f2bf(x - bf2f(h));
    }
}

// ---------------- fused gather + 2-layer MLP via bf16x3 MFMA ----------------
// Block: 32 cells, 256 threads = 4 waves. Wave w owns n-quarter [w*32, w*32+32)
// for BOTH 16-row tiles. X (32x256) staged in LDS as bf16 hi/lo with XOR swizzle.
__device__ __forceinline__ void stage_split(char* lds, int row, int col8, const float* v) {
    unsigned int byte = ((unsigned int)row << 9) + ((unsigned int)col8 << 4);
    byte ^= (unsigned int)(row & 7) << 4;            // G4 swizzle: kill stride-512B conflicts
    bf16x8 hi, lo;
    #pragma unroll
    for (int i = 0; i < 8; i++) {
        u16 h = f2bf(v[i]);
        hi[i] = (short)h;
        lo[i] = (short)f2bf(v[i] - bf2f(h));
    }
    *(bf16x8*)(lds + byte)         = hi;             // X-hi: [0, 16K)
    *(bf16x8*)(lds + 16384 + byte) = lo;             // X-lo: [16K, 32K)
}

__global__ __launch_bounds__(256, 4) void k_mlp(const float* __restrict__ cell_attr,
                                                const float* __restrict__ na,
                                                const int* __restrict__ face,
                                                const u16* __restrict__ w1h,
                                                const u16* __restrict__ w1l,
                                                const u16* __restrict__ w2h,
                                                const u16* __restrict__ w2l,
                                                const float* __restrict__ b1,
                                                const float* __restrict__ b2,
                                                float* __restrict__ out) {
    __shared__ char lds[32768];
    const int t  = threadIdx.x;
    const int c0 = blockIdx.x * 32;

    // ---- stage X = [cell_attr | mean-of-3-nodes] as bf16 hi/lo ----
    {
        const int r = t >> 3;        // 0..31  (cell row within tile)
        const int q = t & 7;         // 0..7   (16-col chunk)
        float v[16];
        const float* pa = cell_attr + (size_t)(c0 + r) * D + q * 16;
        #pragma unroll
        for (int i = 0; i < 4; i++) *(float4*)(v + 4 * i) = *(const float4*)(pa + 4 * i);
        stage_split(lds, r, q * 2,     v);
        stage_split(lds, r, q * 2 + 1, v + 8);

        const int cid = c0 + r;
        const int f0 = face[cid], f1 = face[NC + cid], f2 = face[2 * NC + cid];
        const float* p0 = na + (size_t)f0 * D + q * 16;
        const float* p1 = na + (size_t)f1 * D + q * 16;
        const float* p2 = na + (size_t)f2 * D + q * 16;
        const float third = 1.f / 3.f;
        #pragma unroll
        for (int i = 0; i < 4; i++) {
            float4 a0 = *(const float4*)(p0 + 4 * i);
            float4 a1 = *(const float4*)(p1 + 4 * i);
            float4 a2 = *(const float4*)(p2 + 4 * i);
            v[4 * i + 0] = (a0.x + a1.x + a2.x) * third;
            v[4 * i + 1] = (a0.y + a1.y + a2.y) * third;
            v[4 * i + 2] = (a0.z + a1.z + a2.z) * third;
            v[4 * i + 3] = (a0.w + a1.w + a2.w) * third;
        }
        stage_split(lds, r, 16 + q * 2, v);
        stage_split(lds, r, 17 + q * 2, v + 8);
    }
    __syncthreads();

    const int w  = t >> 6;           // wave 0..3 -> n-quarter
    const int l  = t & 63;
    const int lr = l & 15;           // A row / B-C col within tile
    const int lg = l >> 4;           // k group (8 contiguous k)
    const unsigned int swz = (unsigned int)(lr & 7) << 4;
    const size_t wl8 = (size_t)l * 8;
    const f32x4 z4 = {0.f, 0.f, 0.f, 0.f};
    f32x4 acc[2][2] = {{z4, z4}, {z4, z4}};          // [row-tile][n-tile]

    // ---- GEMM1: X (32x256) @ W1 (256x128), bf16x3 ----
    {
        const unsigned int abase = ((unsigned int)lr << 9) + ((unsigned int)lg << 4);
        const u16* pW1h = w1h + (size_t)(w * 2) * 512 + wl8;
        const u16* pW1l = w1l + (size_t)(w * 2) * 512 + wl8;
        #pragma unroll 2
        for (int kt = 0; kt < 8; ++kt) {
            unsigned int ab = (abase + (unsigned int)kt * 64) ^ swz;
            bf16x8 aH0 = *(const bf16x8*)(lds + ab);
            bf16x8 aL0 = *(const bf16x8*)(lds + 16384 + ab);
            bf16x8 aH1 = *(const bf16x8*)(lds + ab + 8192);          // rows 16..31
            bf16x8 aL1 = *(const bf16x8*)(lds + 16384 + ab + 8192);
            #pragma unroll
            for (int jn = 0; jn < 2; ++jn) {
                size_t fo = (size_t)(kt * 8 + jn) * 512;
                bf16x8 bH = *(const bf16x8*)(pW1h + fo);
                bf16x8 bL = *(const bf16x8*)(pW1l + fo);
                acc[0][jn] = MFMA16(aH0, bL, acc[0][jn]);
                acc[0][jn] = MFMA16(aL0, bH, acc[0][jn]);
                acc[0][jn] = MFMA16(aH0, bH, acc[0][jn]);
                acc[1][jn] = MFMA16(aH1, bL, acc[1][jn]);
                acc[1][jn] = MFMA16(aL1, bH, acc[1][jn]);
                acc[1][jn] = MFMA16(aH1, bH, acc[1][jn]);
            }
        }
    }

    __syncthreads();   // all waves done reading X before H overwrites it

    // ---- bias + relu, re-split H (32x128) into LDS (reuses X-hi region) ----
    #pragma unroll
    for (int jn = 0; jn < 2; ++jn) {
        int col = w * 32 + jn * 16 + lr;
        float bb = b1[col];
        #pragma unroll
        for (int rt = 0; rt < 2; ++rt) {
            #pragma unroll
            for (int r = 0; r < 4; ++r) {
                int row = rt * 16 + lg * 4 + r;       // C/D: row = 4*(lane>>4)+reg
                float h = fmaxf(acc[rt][jn][r] + bb, 0.f);
                u16 hh = f2bf(h);
                u16 hl = f2bf(h - bf2f(hh));
                unsigned int byte = (((unsigned int)row << 8) + ((unsigned int)col << 1))
                                    ^ ((unsigned int)(row & 7) << 4);
                *(u16*)(lds + byte)        = hh;      // H-hi: [0, 8K)
                *(u16*)(lds + 8192 + byte) = hl;      // H-lo: [8K, 16K)
            }
        }
    }
    __syncthreads();

    // ---- GEMM2: H (32x128) @ W2 (128x128), bf16x3 ----
    f32x4 acc2[2][2] = {{z4, z4}, {z4, z4}};
    {
        const unsigned int abase = ((unsigned int)lr << 8) + ((unsigned int)lg << 4);
        const u16* pW2h = w2h + (size_t)(w * 2) * 512 + wl8;
        const u16* pW2l = w2l + (size_t)(w * 2) * 512 + wl8;
        #pragma unroll 2
        for (int kt = 0; kt < 4; ++kt) {
            unsigned int ab = (abase + (unsigned int)kt * 64) ^ swz;
            bf16x8 aH0 = *(const bf16x8*)(lds + ab);
            bf16x8 aL0 = *(const bf16x8*)(lds + 8192 + ab);
            bf16x8 aH1 = *(const bf16x8*)(lds + ab + 4096);          // rows 16..31
            bf16x8 aL1 = *(const bf16x8*)(lds + 8192 + ab + 4096);
            #pragma unroll
            for (int jn = 0; jn < 2; ++jn) {
                size_t fo = (size_t)(kt * 8 + jn) * 512;
                bf16x8 bH = *(const bf16x8*)(pW2h + fo);
                bf16x8 bL = *(const bf16x8*)(pW2l + fo);
                acc2[0][jn] = MFMA16(aH0, bL, acc2[0][jn]);
                acc2[0][jn] = MFMA16(aL0, bH, acc2[0][jn]);
                acc2[0][jn] = MFMA16(aH0, bH, acc2[0][jn]);
                acc2[1][jn] = MFMA16(aH1, bL, acc2[1][jn]);
                acc2[1][jn] = MFMA16(aL1, bH, acc2[1][jn]);
                acc2[1][jn] = MFMA16(aH1, bH, acc2[1][jn]);
            }
        }
    }

    // ---- bias + store ----
    #pragma unroll
    for (int jn = 0; jn < 2; ++jn) {
        int col = w * 32 + jn * 16 + lr;
        float bb = b2[col];
        #pragma unroll
        for (int rt = 0; rt < 2; ++rt) {
            #pragma unroll
            for (int r = 0; r < 4; ++r) {
                int row = c0 + rt * 16 + lg * 4 + r;
                out[(size_t)row * D + col] = acc2[rt][jn][r] + bb;
            }
        }
    }
}

extern "C" void kernel_launch(void* const* d_in, const int* in_sizes, int n_in,
                              void* d_out, int out_size, void* d_ws, size_t ws_size,
                              hipStream_t stream) {
    (void)in_sizes; (void)n_in; (void)out_size; (void)ws_size;
    const float* cell_attr = (const float*)d_in[0];
    const float* edge_attr = (const float*)d_in[1];
    const float* emb       = (const float*)d_in[2];
    const int*   ei        = (const int*)d_in[3];
    const int*   face      = (const int*)d_in[4];
    const float* W1        = (const float*)d_in[5];
    const float* b1        = (const float*)d_in[6];
    const float* W2        = (const float*)d_in[7];
    const float* b2        = (const float*)d_in[8];

    float* out_cell = (float*)d_out;                    // [C*D]
    float* out_node = out_cell + (size_t)NC * D;        // [N*D] (node_agg scratch, then final)

    // ws layout (4B units)
    float* denom  = (float*)d_ws;                 // [N]
    int*   cntA   = (int*)d_ws + NN;              // [N]
    int*   cntF   = cntA + NN;                    // [N]
    int*   curA   = cntF + NN;                    // [N]
    int*   curF   = curA + NN;                    // [N]
    float* expv   = (float*)(curF + NN);          // [2E]
    int*   offA   = (int*)(expv + 2 * NE);        // [N+1]
    int*   offF   = offA + NN + 1;                // [N+1]
    int*   slotsA = offF + NN + 1;                // [2E]
    int*   slotsF = slotsA + 2 * NE;              // [3C]
    int*   bsumA  = slotsF + 3 * NC;              // [512]
    int*   bsumF  = bsumA + 512;                  // [512]

    // W fragment arrays overlay curA/curF (dead after the fill kernels):
    // 192 KB needed, 800 KB available. 16B-aligned (3*NN*4 % 16 == 0).
    u16* w1h = (u16*)curA;                        // 64 frags * 512 u16
    u16* w1l = w1h + 64 * 512;
    u16* w2h = w1l + 64 * 512;                    // 32 frags * 512 u16
    u16* w2l = w2h + 32 * 512;

    const int NB = (NN + 255) / 256;              // 391 scan blocks

    hipMemsetAsync(d_ws, 0, (size_t)5 * NN * 4, stream);   // denom, cntA, cntF, curA, curF

    k_att<<<(NE + 3) / 4, 256, 0, stream>>>(edge_attr, emb, ei, expv, denom);

    k_hist_att <<<(2 * NE + 255) / 256, 256, 0, stream>>>(ei, cntA);
    k_hist_face<<<(3 * NC + 255) / 256, 256, 0, stream>>>(face, cntF);

    k_scan_blocks<<<NB, 256, 0, stream>>>(cntA, bsumA);
    k_scan_top   <<<1, 512, 0, stream>>>(bsumA, NB);
    k_scan_final <<<NB, 256, 0, stream>>>(cntA, bsumA, offA, 2 * NE);

    k_scan_blocks<<<NB, 256, 0, stream>>>(cntF, bsumF);
    k_scan_top   <<<1, 512, 0, stream>>>(bsumF, NB);
    k_scan_final <<<NB, 256, 0, stream>>>(cntF, bsumF, offF, 3 * NC);

    k_fill_att <<<(2 * NE + 255) / 256, 256, 0, stream>>>(ei, offA, curA, slotsA);
    k_fill_face<<<(3 * NC + 255) / 256, 256, 0, stream>>>(face, offF, curF, slotsF);

    // cur arrays are dead now; overlay them with the W fragment split
    k_wsplit<<<24, 256, 0, stream>>>(W1, W2, w1h, w1l, w2h, w2l);

    k_agg_gather<<<(NN + 3) / 4, 256, 0, stream>>>(edge_attr, expv, denom, offA, slotsA, out_node);

    k_mlp<<<NC / 32, 256, 0, stream>>>(cell_attr, out_node, face,
                                       w1h, w1l, w2h, w2l, b1, b2, out_cell);

    k_smean_gather<<<(NN + 3) / 4, 256, 0, stream>>>(out_cell, offF, slotsF, out_node);
}

// Round 2
// 690.582 us; speedup vs baseline: 1.3875x; 1.0837x over previous
//
#include <hip/hip_runtime.h>

#define NN 100000   // nodes
#define NC 200000   // cells
#define NE 300000   // edges
#define D  128
#define NB 391      // scan blocks = ceil(NN/256)
#define AB 37500    // att blocks (8 edges each)
#define HB 2344     // hist blocks = ceil(2E/256) = ceil(3C/256)

typedef unsigned short u16;
typedef __attribute__((ext_vector_type(8))) short bf16x8;  // 8 bf16 = 4 VGPRs
typedef __attribute__((ext_vector_type(4))) float f32x4;   // MFMA accumulator

__device__ __forceinline__ u16 f2bf(float x) {            // fp32 -> bf16 (RNE)
    unsigned int u = __float_as_uint(x);
    u += 0x7fffu + ((u >> 16) & 1u);
    return (u16)(u >> 16);
}
__device__ __forceinline__ float bf2f(u16 h) {
    return __uint_as_float((unsigned int)h << 16);
}
// packed f32x2 -> bf16x2 (low16 = a, high16 = b); no builtin on gfx950
__device__ __forceinline__ unsigned int cvt_pk_bf16(float a, float b) {
    unsigned int r;
    asm("v_cvt_pk_bf16_f32 %0, %1, %2" : "=v"(r) : "v"(a), "v"(b));
    return r;
}

#define MFMA16(a, b, c) __builtin_amdgcn_mfma_f32_16x16x32_bf16((a), (b), (c), 0, 0, 0)

// ================= fused: attention logits + both histograms + W split ==========
__global__ __launch_bounds__(256) void k_att_prep(const float* __restrict__ edge_attr,
                                                  const float* __restrict__ emb,
                                                  const int* __restrict__ ei,
                                                  const int* __restrict__ face,
                                                  float* __restrict__ expv,
                                                  float* __restrict__ denom,
                                                  int* __restrict__ cntA,
                                                  int* __restrict__ cntF,
                                                  const float* __restrict__ W1,
                                                  const float* __restrict__ W2,
                                                  u16* __restrict__ w1h, u16* __restrict__ w1l,
                                                  u16* __restrict__ w2h, u16* __restrict__ w2l) {
    int b = blockIdx.x;
    int t = threadIdx.x;
    if (b < AB) {
        // ---- attention: 8 edges/block, half-wave (32 lanes, float4) per edge ----
        int lane = t & 63;
        int half = lane >> 5;
        int sub  = lane & 31;
        int e = b * 8 + (t >> 6) * 2 + half;          // AB*8 == NE exactly
        int send = ei[e];
        int recv = ei[NE + e];
        float4 a  = ((const float4*)(edge_attr + (size_t)e * D))[sub];
        float4 r4 = ((const float4*)(emb + (size_t)recv * D))[sub];
        float4 s4 = ((const float4*)(emb + (size_t)send * D))[sub];
        float dr = a.x * r4.x + a.y * r4.y + a.z * r4.z + a.w * r4.w;
        float ds = a.x * s4.x + a.y * s4.y + a.z * s4.z + a.w * s4.w;
        #pragma unroll
        for (int off = 16; off > 0; off >>= 1) {
            dr += __shfl_xor(dr, off);
            ds += __shfl_xor(ds, off);
        }
        if (sub == 0) {
            const float inv_scale = 0.08838834764831845f; // 1/sqrt(128)
            float er = __expf(dr * inv_scale);
            float es = __expf(ds * inv_scale);
            expv[e] = er;
            expv[NE + e] = es;
            atomicAdd(&denom[recv], er);
            atomicAdd(&denom[send], es);
        }
    } else if (b < AB + HB) {
        int i = (b - AB) * 256 + t;
        if (i >= 2 * NE) return;
        int tgt = (i < NE) ? ei[NE + i] : ei[i - NE];
        atomicAdd(&cntA[tgt], 1);
    } else if (b < AB + 2 * HB) {
        int i = (b - AB - HB) * 256 + t;
        if (i >= 3 * NC) return;
        atomicAdd(&cntF[face[i]], 1);
    } else {
        // ---- W prepack: fragment-major bf16 hi/lo split ----
        int tid = (b - AB - 2 * HB) * 256 + t;
        if (tid >= 6144) return;
        int l = tid & 63;
        int f = tid >> 6;
        const float* W; u16 *oh, *ol; int fi;
        if (f < 64) { W = W1; oh = w1h; ol = w1l; fi = f; }
        else        { W = W2; oh = w2h; ol = w2l; fi = f - 64; }
        int kt = fi >> 3, nt = fi & 7;
        int k0 = kt * 32 + 8 * (l >> 4);
        int n  = nt * 16 + (l & 15);
        #pragma unroll
        for (int i = 0; i < 8; i++) {
            float x = W[(size_t)(k0 + i) * 128 + n];
            u16 h = f2bf(x);
            oh[(size_t)fi * 512 + l * 8 + i] = h;
            ol[(size_t)fi * 512 + l * 8 + i] = f2bf(x - bf2f(h));
        }
    }
}

// ================= CSR scan (both arrays in one grid) =================
__global__ __launch_bounds__(256) void k_scan_blocks(const int* __restrict__ cntA,
                                                     const int* __restrict__ cntF,
                                                     int* __restrict__ bsumA,
                                                     int* __restrict__ bsumF) {
    __shared__ int s[256];
    int bb = blockIdx.x;
    bool fa = bb >= NB;
    const int* cnt = fa ? cntF : cntA;
    int* bsum = fa ? bsumF : bsumA;
    int blk = fa ? bb - NB : bb;
    int t = threadIdx.x;
    int i = blk * 256 + t;
    s[t] = (i < NN) ? cnt[i] : 0;
    __syncthreads();
    #pragma unroll
    for (int off = 128; off > 0; off >>= 1) {
        if (t < off) s[t] += s[t + off];
        __syncthreads();
    }
    if (t == 0) bsum[blk] = s[0];
}

__global__ __launch_bounds__(512) void k_scan_top(int* __restrict__ bsumA,
                                                  int* __restrict__ bsumF, int nb) {
    __shared__ int s[512];
    int* bsum = blockIdx.x ? bsumF : bsumA;
    int t = threadIdx.x;
    int v = (t < nb) ? bsum[t] : 0;
    s[t] = v;
    __syncthreads();
    #pragma unroll
    for (int off = 1; off < 512; off <<= 1) {
        int x = (t >= off) ? s[t - off] : 0;
        __syncthreads();
        s[t] += x;
        __syncthreads();
    }
    if (t < nb) bsum[t] = s[t] - v;   // exclusive
}

__global__ __launch_bounds__(256) void k_scan_final(const int* __restrict__ cntA,
                                                    const int* __restrict__ cntF,
                                                    const int* __restrict__ bsumA,
                                                    const int* __restrict__ bsumF,
                                                    int* __restrict__ offA,
                                                    int* __restrict__ offF) {
    __shared__ int s[256];
    int bb = blockIdx.x;
    bool fa = bb >= NB;
    const int* cnt = fa ? cntF : cntA;
    const int* bsum = fa ? bsumF : bsumA;
    int* off_out = fa ? offF : offA;
    int total = fa ? 3 * NC : 2 * NE;
    int blk = fa ? bb - NB : bb;
    int t = threadIdx.x;
    int i = blk * 256 + t;
    int v = (i < NN) ? cnt[i] : 0;
    s[t] = v;
    __syncthreads();
    #pragma unroll
    for (int off = 1; off < 256; off <<= 1) {
        int x = (t >= off) ? s[t - off] : 0;
        __syncthreads();
        s[t] += x;
        __syncthreads();
    }
    if (i < NN) off_out[i] = s[t] - v + bsum[blk];
    if (i == 0) off_out[NN] = total;
}

// ================= fill (att slots + streamed weights, face slots) =================
__global__ __launch_bounds__(256) void k_fill(const int* __restrict__ ei,
                                              const float* __restrict__ expv,
                                              const int* __restrict__ face,
                                              const int* __restrict__ offA,
                                              const int* __restrict__ offF,
                                              int* __restrict__ curA,
                                              int* __restrict__ curF,
                                              int* __restrict__ slotsA,
                                              float* __restrict__ wexpA,
                                              int* __restrict__ slotsF) {
    int b = blockIdx.x;
    int t = threadIdx.x;
    if (b < HB) {
        int i = b * 256 + t;
        if (i >= 2 * NE) return;
        int tgt = (i < NE) ? ei[NE + i] : ei[i - NE];
        int pos = offA[tgt] + atomicAdd(&curA[tgt], 1);
        slotsA[pos] = (i < NE) ? i : i - NE;          // edge row directly
        wexpA[pos] = expv[i];                         // weight in slot order
    } else {
        int i = (b - HB) * 256 + t;
        if (i >= 3 * NC) return;
        int tgt = face[i];
        int pos = offF[tgt] + atomicAdd(&curF[tgt], 1);
        int c = i; if (c >= NC) c -= NC; if (c >= NC) c -= NC;   // cell id = i mod NC
        slotsF[pos] = c;
    }
}

// ================= gather-style node aggregation (no atomics) =================
__global__ __launch_bounds__(256) void k_agg_gather(const float* __restrict__ edge_attr,
                                                    const float* __restrict__ wexp,
                                                    const float* __restrict__ denom,
                                                    const int* __restrict__ offs,
                                                    const int* __restrict__ slots,
                                                    float* __restrict__ na) {
    int n = blockIdx.x * 4 + (threadIdx.x >> 6);
    int lane = threadIdx.x & 63;
    int half = lane >> 5, sub = lane & 31;
    if (n >= NN) return;
    int s0 = offs[n], s1 = offs[n + 1];
    float4 acc = {0.f, 0.f, 0.f, 0.f};
    for (int s = s0 + half; s < s1; s += 2) {
        int row = slots[s];
        float w = wexp[s];
        float4 a = ((const float4*)(edge_attr + (size_t)row * D))[sub];
        acc.x += w * a.x; acc.y += w * a.y; acc.z += w * a.z; acc.w += w * a.w;
    }
    acc.x += __shfl_xor(acc.x, 32);
    acc.y += __shfl_xor(acc.y, 32);
    acc.z += __shfl_xor(acc.z, 32);
    acc.w += __shfl_xor(acc.w, 32);
    if (half == 0) {
        float inv = (s1 > s0) ? 1.f / denom[n] : 0.f;
        float4 r; r.x = acc.x * inv; r.y = acc.y * inv; r.z = acc.z * inv; r.w = acc.w * inv;
        ((float4*)(na + (size_t)n * D))[sub] = r;
    }
}

// ================= gather-style scatter-mean (no atomics) =================
__global__ __launch_bounds__(256) void k_smean_gather(const float* __restrict__ cell_out,
                                                      const int* __restrict__ offs,
                                                      const int* __restrict__ slots,
                                                      float* __restrict__ node_out) {
    int n = blockIdx.x * 4 + (threadIdx.x >> 6);
    int lane = threadIdx.x & 63;
    int half = lane >> 5, sub = lane & 31;
    if (n >= NN) return;
    int s0 = offs[n], s1 = offs[n + 1];
    float4 acc = {0.f, 0.f, 0.f, 0.f};
    for (int s = s0 + half; s < s1; s += 2) {
        int c = slots[s];
        float4 y = ((const float4*)(cell_out + (size_t)c * D))[sub];
        acc.x += y.x; acc.y += y.y; acc.z += y.z; acc.w += y.w;
    }
    acc.x += __shfl_xor(acc.x, 32);
    acc.y += __shfl_xor(acc.y, 32);
    acc.z += __shfl_xor(acc.z, 32);
    acc.w += __shfl_xor(acc.w, 32);
    if (half == 0) {
        int deg = s1 - s0;
        float inv = deg ? 1.f / (float)deg : 0.f;
        float4 r; r.x = acc.x * inv; r.y = acc.y * inv; r.z = acc.z * inv; r.w = acc.w * inv;
        ((float4*)(node_out + (size_t)n * D))[sub] = r;
    }
}

// ================= fused gather + 2-layer MLP via bf16x3 MFMA =================
// Block: 32 cells, 256 threads = 4 waves. Wave w owns n-quarter [w*32, w*32+32)
// for BOTH 16-row tiles. X (32x256) staged in LDS as bf16 hi/lo with XOR swizzle.
__device__ __forceinline__ void stage_split(char* lds, int row, int col8, const float* v) {
    unsigned int byte = ((unsigned int)row << 9) + ((unsigned int)col8 << 4);
    byte ^= (unsigned int)(row & 7) << 4;            // G4 swizzle: kill stride-512B conflicts
    uint4 hi, lo;
    unsigned int* hp = (unsigned int*)&hi;
    unsigned int* lp = (unsigned int*)&lo;
    #pragma unroll
    for (int i = 0; i < 4; i++) {
        unsigned int h = cvt_pk_bf16(v[2 * i], v[2 * i + 1]);
        float h0 = __uint_as_float(h << 16);
        float h1 = __uint_as_float(h & 0xffff0000u);
        hp[i] = h;
        lp[i] = cvt_pk_bf16(v[2 * i] - h0, v[2 * i + 1] - h1);
    }
    *(uint4*)(lds + byte)         = hi;              // X-hi: [0, 16K)
    *(uint4*)(lds + 16384 + byte) = lo;              // X-lo: [16K, 32K)
}

__global__ __launch_bounds__(256, 4) void k_mlp(const float* __restrict__ cell_attr,
                                                const float* __restrict__ na,
                                                const int* __restrict__ face,
                                                const u16* __restrict__ w1h,
                                                const u16* __restrict__ w1l,
                                                const u16* __restrict__ w2h,
                                                const u16* __restrict__ w2l,
                                                const float* __restrict__ b1,
                                                const float* __restrict__ b2,
                                                float* __restrict__ out) {
    __shared__ char lds[32768];
    const int t  = threadIdx.x;
    const int c0 = blockIdx.x * 32;

    // ---- stage X = [cell_attr | mean-of-3-nodes] as bf16 hi/lo ----
    {
        const int r = t >> 3;        // 0..31  (cell row within tile)
        const int q = t & 7;         // 0..7   (16-col chunk)
        float v[16];
        const float* pa = cell_attr + (size_t)(c0 + r) * D + q * 16;
        #pragma unroll
        for (int i = 0; i < 4; i++) *(float4*)(v + 4 * i) = *(const float4*)(pa + 4 * i);
        stage_split(lds, r, q * 2,     v);
        stage_split(lds, r, q * 2 + 1, v + 8);

        const int cid = c0 + r;
        const int f0 = face[cid], f1 = face[NC + cid], f2 = face[2 * NC + cid];
        const float* p0 = na + (size_t)f0 * D + q * 16;
        const float* p1 = na + (size_t)f1 * D + q * 16;
        const float* p2 = na + (size_t)f2 * D + q * 16;
        const float third = 1.f / 3.f;
        #pragma unroll
        for (int i = 0; i < 4; i++) {
            float4 a0 = *(const float4*)(p0 + 4 * i);
            float4 a1 = *(const float4*)(p1 + 4 * i);
            float4 a2 = *(const float4*)(p2 + 4 * i);
            v[4 * i + 0] = (a0.x + a1.x + a2.x) * third;
            v[4 * i + 1] = (a0.y + a1.y + a2.y) * third;
            v[4 * i + 2] = (a0.z + a1.z + a2.z) * third;
            v[4 * i + 3] = (a0.w + a1.w + a2.w) * third;
        }
        stage_split(lds, r, 16 + q * 2, v);
        stage_split(lds, r, 17 + q * 2, v + 8);
    }
    __syncthreads();

    const int w  = t >> 6;           // wave 0..3 -> n-quarter
    const int l  = t & 63;
    const int lr = l & 15;           // A row / B-C col within tile
    const int lg = l >> 4;           // k group (8 contiguous k)
    const unsigned int swz = (unsigned int)(lr & 7) << 4;
    const size_t wl8 = (size_t)l * 8;
    const f32x4 z4 = {0.f, 0.f, 0.f, 0.f};
    f32x4 acc[2][2] = {{z4, z4}, {z4, z4}};          // [row-tile][n-tile]

    // ---- GEMM1: X (32x256) @ W1 (256x128), bf16x3 ----
    {
        const unsigned int abase = ((unsigned int)lr << 9) + ((unsigned int)lg << 4);
        const u16* pW1h = w1h + (size_t)(w * 2) * 512 + wl8;
        const u16* pW1l = w1l + (size_t)(w * 2) * 512 + wl8;
        #pragma unroll 2
        for (int kt = 0; kt < 8; ++kt) {
            unsigned int ab = (abase + (unsigned int)kt * 64) ^ swz;
            bf16x8 aH0 = *(const bf16x8*)(lds + ab);
            bf16x8 aL0 = *(const bf16x8*)(lds + 16384 + ab);
            bf16x8 aH1 = *(const bf16x8*)(lds + ab + 8192);          // rows 16..31
            bf16x8 aL1 = *(const bf16x8*)(lds + 16384 + ab + 8192);
            #pragma unroll
            for (int jn = 0; jn < 2; ++jn) {
                size_t fo = (size_t)(kt * 8 + jn) * 512;
                bf16x8 bH = *(const bf16x8*)(pW1h + fo);
                bf16x8 bL = *(const bf16x8*)(pW1l + fo);
                acc[0][jn] = MFMA16(aH0, bL, acc[0][jn]);
                acc[0][jn] = MFMA16(aL0, bH, acc[0][jn]);
                acc[0][jn] = MFMA16(aH0, bH, acc[0][jn]);
                acc[1][jn] = MFMA16(aH1, bL, acc[1][jn]);
                acc[1][jn] = MFMA16(aL1, bH, acc[1][jn]);
                acc[1][jn] = MFMA16(aH1, bH, acc[1][jn]);
            }
        }
    }

    __syncthreads();   // all waves done reading X before H overwrites it

    // ---- bias + relu, re-split H (32x128) into LDS (reuses X-hi region) ----
    {
        const int col0 = w * 32 + lr;          // jn = 0
        const int col1 = col0 + 16;            // jn = 1
        const float bb0 = b1[col0];
        const float bb1 = b1[col1];
        #pragma unroll
        for (int rt = 0; rt < 2; ++rt) {
            #pragma unroll
            for (int r = 0; r < 4; ++r) {
                int row = rt * 16 + lg * 4 + r;       // C/D: row = 4*(lane>>4)+reg
                float h0 = fmaxf(acc[rt][0][r] + bb0, 0.f);
                float h1 = fmaxf(acc[rt][1][r] + bb1, 0.f);
                unsigned int ph = cvt_pk_bf16(h0, h1);
                float f0 = __uint_as_float(ph << 16);
                float f1 = __uint_as_float(ph & 0xffff0000u);
                unsigned int pl = cvt_pk_bf16(h0 - f0, h1 - f1);
                unsigned int swzr = (unsigned int)(row & 7) << 4;
                unsigned int b0 = (((unsigned int)row << 8) + ((unsigned int)col0 << 1)) ^ swzr;
                unsigned int bcol1 = (((unsigned int)row << 8) + ((unsigned int)col1 << 1)) ^ swzr;
                *(u16*)(lds + b0)            = (u16)ph;       // H-hi: [0, 8K)
                *(u16*)(lds + bcol1)         = (u16)(ph >> 16);
                *(u16*)(lds + 8192 + b0)     = (u16)pl;       // H-lo: [8K, 16K)
                *(u16*)(lds + 8192 + bcol1)  = (u16)(pl >> 16);
            }
        }
    }
    __syncthreads();

    // ---- GEMM2: H (32x128) @ W2 (128x128), bf16x3 ----
    f32x4 acc2[2][2] = {{z4, z4}, {z4, z4}};
    {
        const unsigned int abase = ((unsigned int)lr << 8) + ((unsigned int)lg << 4);
        const u16* pW2h = w2h + (size_t)(w * 2) * 512 + wl8;
        const u16* pW2l = w2l + (size_t)(w * 2) * 512 + wl8;
        #pragma unroll 2
        for (int kt = 0; kt < 4; ++kt) {
            unsigned int ab = (abase + (unsigned int)kt * 64) ^ swz;
            bf16x8 aH0 = *(const bf16x8*)(lds + ab);
            bf16x8 aL0 = *(const bf16x8*)(lds + 8192 + ab);
            bf16x8 aH1 = *(const bf16x8*)(lds + ab + 4096);          // rows 16..31
            bf16x8 aL1 = *(const bf16x8*)(lds + 8192 + ab + 4096);
            #pragma unroll
            for (int jn = 0; jn < 2; ++jn) {
                size_t fo = (size_t)(kt * 8 + jn) * 512;
                bf16x8 bH = *(const bf16x8*)(pW2h + fo);
                bf16x8 bL = *(const bf16x8*)(pW2l + fo);
                acc2[0][jn] = MFMA16(aH0, bL, acc2[0][jn]);
                acc2[0][jn] = MFMA16(aL0, bH, acc2[0][jn]);
                acc2[0][jn] = MFMA16(aH0, bH, acc2[0][jn]);
                acc2[1][jn] = MFMA16(aH1, bL, acc2[1][jn]);
                acc2[1][jn] = MFMA16(aL1, bH, acc2[1][jn]);
                acc2[1][jn] = MFMA16(aH1, bH, acc2[1][jn]);
            }
        }
    }

    // ---- bias + store ----
    #pragma unroll
    for (int jn = 0; jn < 2; ++jn) {
        int col = w * 32 + jn * 16 + lr;
        float bb = b2[col];
        #pragma unroll
        for (int rt = 0; rt < 2; ++rt) {
            #pragma unroll
            for (int r = 0; r < 4; ++r) {
                int row = c0 + rt * 16 + lg * 4 + r;
                out[(size_t)row * D + col] = acc2[rt][jn][r] + bb;
            }
        }
    }
}

extern "C" void kernel_launch(void* const* d_in, const int* in_sizes, int n_in,
                              void* d_out, int out_size, void* d_ws, size_t ws_size,
                              hipStream_t stream) {
    (void)in_sizes; (void)n_in; (void)out_size; (void)ws_size;
    const float* cell_attr = (const float*)d_in[0];
    const float* edge_attr = (const float*)d_in[1];
    const float* emb       = (const float*)d_in[2];
    const int*   ei        = (const int*)d_in[3];
    const int*   face      = (const int*)d_in[4];
    const float* W1        = (const float*)d_in[5];
    const float* b1        = (const float*)d_in[6];
    const float* W2        = (const float*)d_in[7];
    const float* b2        = (const float*)d_in[8];

    float* out_cell = (float*)d_out;                    // [C*D]
    float* out_node = out_cell + (size_t)NC * D;        // [N*D] (node_agg scratch, then final)

    // ws layout (4B units)
    float* denom  = (float*)d_ws;                 // [N]
    int*   cntA   = (int*)d_ws + NN;              // [N]
    int*   cntF   = cntA + NN;                    // [N]
    int*   curA   = cntF + NN;                    // [N]
    int*   curF   = curA + NN;                    // [N]
    float* expv   = (float*)(curF + NN);          // [2E]
    int*   offA   = (int*)(expv + 2 * NE);        // [N+1]
    int*   offF   = offA + NN + 1;                // [N+1]
    int*   slotsA = offF + NN + 1;                // [2E]
    int*   slotsF = slotsA + 2 * NE;              // [3C]
    float* wexpA  = (float*)(slotsF + 3 * NC);    // [2E]
    int*   bsumA  = (int*)(wexpA + 2 * NE);       // [512]
    int*   bsumF  = bsumA + 512;                  // [512]
    // W fragment arrays (fresh region, 16B-aligned): 192 KB
    u16* w1h = (u16*)(((uintptr_t)(bsumF + 512) + 15) & ~(uintptr_t)15);
    u16* w1l = w1h + 64 * 512;
    u16* w2h = w1l + 64 * 512;                    // 32 frags * 512 u16
    u16* w2l = w2h + 32 * 512;

    hipMemsetAsync(d_ws, 0, (size_t)5 * NN * 4, stream);   // denom, cntA, cntF, curA, curF

    k_att_prep<<<AB + 2 * HB + 24, 256, 0, stream>>>(edge_attr, emb, ei, face, expv, denom,
                                                     cntA, cntF, W1, W2, w1h, w1l, w2h, w2l);

    k_scan_blocks<<<2 * NB, 256, 0, stream>>>(cntA, cntF, bsumA, bsumF);
    k_scan_top   <<<2, 512, 0, stream>>>(bsumA, bsumF, NB);
    k_scan_final <<<2 * NB, 256, 0, stream>>>(cntA, cntF, bsumA, bsumF, offA, offF);

    k_fill<<<2 * HB, 256, 0, stream>>>(ei, expv, face, offA, offF, curA, curF,
                                       slotsA, wexpA, slotsF);

    k_agg_gather<<<(NN + 3) / 4, 256, 0, stream>>>(edge_attr, wexpA, denom, offA, slotsA, out_node);

    k_mlp<<<NC / 32, 256, 0, stream>>>(cell_attr, out_node, face,
                                       w1h, w1l, w2h, w2l, b1, b2, out_cell);

    k_smean_gather<<<(NN + 3) / 4, 256, 0, stream>>>(out_cell, offF, slotsF, out_node);
}

// Round 3
// 665.829 us; speedup vs baseline: 1.4391x; 1.0372x over previous
//
#include <hip/hip_runtime.h>

#define NN 100000   // nodes
#define NC 200000   // cells
#define NE 300000   // edges
#define D  128
#define NB 391      // scan blocks = ceil(NN/256)
#define ATT_B 2048  // persistent attention blocks (grid-stride)
#define HB 2344     // hist blocks = ceil(2E/256) = ceil(3C/256)

typedef unsigned short u16;
typedef __attribute__((ext_vector_type(8))) short bf16x8;  // 8 bf16 = 4 VGPRs
typedef __attribute__((ext_vector_type(4))) float f32x4;   // MFMA accumulator

__device__ __forceinline__ u16 f2bf(float x) {            // fp32 -> bf16 (RNE)
    unsigned int u = __float_as_uint(x);
    u += 0x7fffu + ((u >> 16) & 1u);
    return (u16)(u >> 16);
}
__device__ __forceinline__ float bf2f(u16 h) {
    return __uint_as_float((unsigned int)h << 16);
}
// packed f32x2 -> bf16x2 (low16 = a, high16 = b); no builtin on gfx950
__device__ __forceinline__ unsigned int cvt_pk_bf16(float a, float b) {
    unsigned int r;
    asm("v_cvt_pk_bf16_f32 %0, %1, %2" : "=v"(r) : "v"(a), "v"(b));
    return r;
}

#define MFMA16(a, b, c) __builtin_amdgcn_mfma_f32_16x16x32_bf16((a), (b), (c), 0, 0, 0)

// ====== fused: attention logits (grid-stride, 2-deep) + histograms + W split ======
__global__ __launch_bounds__(256) void k_att_prep(const float* __restrict__ edge_attr,
                                                  const float* __restrict__ emb,
                                                  const int* __restrict__ ei,
                                                  const int* __restrict__ face,
                                                  float* __restrict__ expv,
                                                  float* __restrict__ denom,
                                                  int* __restrict__ cntA,
                                                  int* __restrict__ cntF,
                                                  const float* __restrict__ W1,
                                                  const float* __restrict__ W2,
                                                  u16* __restrict__ w1h, u16* __restrict__ w1l,
                                                  u16* __restrict__ w2h, u16* __restrict__ w2l) {
    int b = blockIdx.x;
    int t = threadIdx.x;
    if (b < ATT_B) {
        const int HW = ATT_B * 8;              // total half-waves
        int hw  = b * 8 + (t >> 5);
        int sub = t & 31;
        const float inv_scale = 0.08838834764831845f; // 1/sqrt(128)
        for (int e0 = hw; e0 < NE; e0 += 2 * HW) {
            int e1 = e0 + HW;
            bool h1 = (e1 < NE);
            int sd0 = ei[e0], rc0 = ei[NE + e0];
            int sd1 = h1 ? ei[e1] : 0;
            int rc1 = h1 ? ei[NE + e1] : 0;
            float4 a0 = ((const float4*)(edge_attr + (size_t)e0 * D))[sub];
            float4 r0 = ((const float4*)(emb + (size_t)rc0 * D))[sub];
            float4 s0 = ((const float4*)(emb + (size_t)sd0 * D))[sub];
            float dr0 = a0.x * r0.x + a0.y * r0.y + a0.z * r0.z + a0.w * r0.w;
            float ds0 = a0.x * s0.x + a0.y * s0.y + a0.z * s0.z + a0.w * s0.w;
            float dr1 = 0.f, ds1 = 0.f;
            if (h1) {
                float4 a1 = ((const float4*)(edge_attr + (size_t)e1 * D))[sub];
                float4 r1 = ((const float4*)(emb + (size_t)rc1 * D))[sub];
                float4 s1 = ((const float4*)(emb + (size_t)sd1 * D))[sub];
                dr1 = a1.x * r1.x + a1.y * r1.y + a1.z * r1.z + a1.w * r1.w;
                ds1 = a1.x * s1.x + a1.y * s1.y + a1.z * s1.z + a1.w * s1.w;
            }
            #pragma unroll
            for (int off = 16; off > 0; off >>= 1) {
                dr0 += __shfl_xor(dr0, off);
                ds0 += __shfl_xor(ds0, off);
                dr1 += __shfl_xor(dr1, off);
                ds1 += __shfl_xor(ds1, off);
            }
            if (sub == 0) {
                float er = __expf(dr0 * inv_scale);
                float es = __expf(ds0 * inv_scale);
                expv[e0] = er;
                expv[NE + e0] = es;
                atomicAdd(&denom[rc0], er);
                atomicAdd(&denom[sd0], es);
                if (h1) {
                    float er1 = __expf(dr1 * inv_scale);
                    float es1 = __expf(ds1 * inv_scale);
                    expv[e1] = er1;
                    expv[NE + e1] = es1;
                    atomicAdd(&denom[rc1], er1);
                    atomicAdd(&denom[sd1], es1);
                }
            }
        }
    } else if (b < ATT_B + HB) {
        int i = (b - ATT_B) * 256 + t;
        if (i >= 2 * NE) return;
        int tgt = (i < NE) ? ei[NE + i] : ei[i - NE];
        atomicAdd(&cntA[tgt], 1);
    } else if (b < ATT_B + 2 * HB) {
        int i = (b - ATT_B - HB) * 256 + t;
        if (i >= 3 * NC) return;
        atomicAdd(&cntF[face[i]], 1);
    } else {
        // ---- W prepack: fragment-major bf16 hi/lo split ----
        int tid = (b - ATT_B - 2 * HB) * 256 + t;
        if (tid >= 6144) return;
        int l = tid & 63;
        int f = tid >> 6;
        const float* W; u16 *oh, *ol; int fi;
        if (f < 64) { W = W1; oh = w1h; ol = w1l; fi = f; }
        else        { W = W2; oh = w2h; ol = w2l; fi = f - 64; }
        int kt = fi >> 3, nt = fi & 7;
        int k0 = kt * 32 + 8 * (l >> 4);
        int n  = nt * 16 + (l & 15);
        #pragma unroll
        for (int i = 0; i < 8; i++) {
            float x = W[(size_t)(k0 + i) * 128 + n];
            u16 h = f2bf(x);
            oh[(size_t)fi * 512 + l * 8 + i] = h;
            ol[(size_t)fi * 512 + l * 8 + i] = f2bf(x - bf2f(h));
        }
    }
}

// ================= CSR scan (both arrays in one grid) =================
__global__ __launch_bounds__(256) void k_scan_blocks(const int* __restrict__ cntA,
                                                     const int* __restrict__ cntF,
                                                     int* __restrict__ bsumA,
                                                     int* __restrict__ bsumF) {
    __shared__ int s[256];
    int bb = blockIdx.x;
    bool fa = bb >= NB;
    const int* cnt = fa ? cntF : cntA;
    int* bsum = fa ? bsumF : bsumA;
    int blk = fa ? bb - NB : bb;
    int t = threadIdx.x;
    int i = blk * 256 + t;
    s[t] = (i < NN) ? cnt[i] : 0;
    __syncthreads();
    #pragma unroll
    for (int off = 128; off > 0; off >>= 1) {
        if (t < off) s[t] += s[t + off];
        __syncthreads();
    }
    if (t == 0) bsum[blk] = s[0];
}

__global__ __launch_bounds__(512) void k_scan_top(int* __restrict__ bsumA,
                                                  int* __restrict__ bsumF, int nb) {
    __shared__ int s[512];
    int* bsum = blockIdx.x ? bsumF : bsumA;
    int t = threadIdx.x;
    int v = (t < nb) ? bsum[t] : 0;
    s[t] = v;
    __syncthreads();
    #pragma unroll
    for (int off = 1; off < 512; off <<= 1) {
        int x = (t >= off) ? s[t - off] : 0;
        __syncthreads();
        s[t] += x;
        __syncthreads();
    }
    if (t < nb) bsum[t] = s[t] - v;   // exclusive
}

__global__ __launch_bounds__(256) void k_scan_final(const int* __restrict__ cntA,
                                                    const int* __restrict__ cntF,
                                                    const int* __restrict__ bsumA,
                                                    const int* __restrict__ bsumF,
                                                    int* __restrict__ offA,
                                                    int* __restrict__ offF) {
    __shared__ int s[256];
    int bb = blockIdx.x;
    bool fa = bb >= NB;
    const int* cnt = fa ? cntF : cntA;
    const int* bsum = fa ? bsumF : bsumA;
    int* off_out = fa ? offF : offA;
    int total = fa ? 3 * NC : 2 * NE;
    int blk = fa ? bb - NB : bb;
    int t = threadIdx.x;
    int i = blk * 256 + t;
    int v = (i < NN) ? cnt[i] : 0;
    s[t] = v;
    __syncthreads();
    #pragma unroll
    for (int off = 1; off < 256; off <<= 1) {
        int x = (t >= off) ? s[t - off] : 0;
        __syncthreads();
        s[t] += x;
        __syncthreads();
    }
    if (i < NN) off_out[i] = s[t] - v + bsum[blk];
    if (i == 0) off_out[NN] = total;
}

// ===== fill (att slot+weight packed as int2, face slots) =====
__global__ __launch_bounds__(256) void k_fill(const int* __restrict__ ei,
                                              const float* __restrict__ expv,
                                              const int* __restrict__ face,
                                              const int* __restrict__ offA,
                                              const int* __restrict__ offF,
                                              int* __restrict__ curA,
                                              int* __restrict__ curF,
                                              int2* __restrict__ swA,
                                              int* __restrict__ slotsF) {
    int b = blockIdx.x;
    int t = threadIdx.x;
    if (b < HB) {
        int i = b * 256 + t;
        if (i >= 2 * NE) return;
        int tgt = (i < NE) ? ei[NE + i] : ei[i - NE];
        int pos = offA[tgt] + atomicAdd(&curA[tgt], 1);
        int2 p;
        p.x = (i < NE) ? i : i - NE;              // edge row
        p.y = __float_as_int(expv[i]);            // weight
        swA[pos] = p;
    } else {
        int i = (b - HB) * 256 + t;
        if (i >= 3 * NC) return;
        int tgt = face[i];
        int pos = offF[tgt] + atomicAdd(&curF[tgt], 1);
        int c = i; if (c >= NC) c -= NC; if (c >= NC) c -= NC;   // cell id = i mod NC
        slotsF[pos] = c;
    }
}

// ===== node aggregation: register-batched gathers, full wave per node =====
__global__ __launch_bounds__(256) void k_agg_gather(const float* __restrict__ edge_attr,
                                                    const int2* __restrict__ swA,
                                                    const float* __restrict__ denom,
                                                    const int* __restrict__ offs,
                                                    float* __restrict__ na) {
    int n = blockIdx.x * 4 + (threadIdx.x >> 6);
    int lane = threadIdx.x & 63;
    if (n >= NN) return;
    int s0 = offs[n], s1 = offs[n + 1];
    int deg = s1 - s0;
    float2 acc = {0.f, 0.f};
    int base = 0;
    while (base < deg) {
        int chunk = deg - base;
        if (chunk > 64) chunk = 64;
        int sl = 0; float wl = 0.f;
        if (lane < chunk) {
            int2 p = swA[s0 + base + lane];
            sl = p.x;
            wl = __int_as_float(p.y);
        }
        int j = 0;
        for (; j + 4 <= chunk; j += 4) {
            int r0 = __shfl(sl, j),     r1 = __shfl(sl, j + 1);
            int r2 = __shfl(sl, j + 2), r3 = __shfl(sl, j + 3);
            float w0 = __shfl(wl, j),     w1 = __shfl(wl, j + 1);
            float w2 = __shfl(wl, j + 2), w3 = __shfl(wl, j + 3);
            float2 a0 = ((const float2*)(edge_attr + (size_t)r0 * D))[lane];
            float2 a1 = ((const float2*)(edge_attr + (size_t)r1 * D))[lane];
            float2 a2 = ((const float2*)(edge_attr + (size_t)r2 * D))[lane];
            float2 a3 = ((const float2*)(edge_attr + (size_t)r3 * D))[lane];
            acc.x += w0 * a0.x + w1 * a1.x + w2 * a2.x + w3 * a3.x;
            acc.y += w0 * a0.y + w1 * a1.y + w2 * a2.y + w3 * a3.y;
        }
        for (; j < chunk; ++j) {
            int rr = __shfl(sl, j);
            float ww = __shfl(wl, j);
            float2 a = ((const float2*)(edge_attr + (size_t)rr * D))[lane];
            acc.x += ww * a.x;
            acc.y += ww * a.y;
        }
        base += chunk;
    }
    float inv = (deg > 0) ? 1.f / denom[n] : 0.f;
    float2 r; r.x = acc.x * inv; r.y = acc.y * inv;
    ((float2*)(na + (size_t)n * D))[lane] = r;
}

// ===== scatter-mean: register-batched gathers, full wave per node =====
__global__ __launch_bounds__(256) void k_smean_gather(const float* __restrict__ cell_out,
                                                      const int* __restrict__ offs,
                                                      const int* __restrict__ slots,
                                                      float* __restrict__ node_out) {
    int n = blockIdx.x * 4 + (threadIdx.x >> 6);
    int lane = threadIdx.x & 63;
    if (n >= NN) return;
    int s0 = offs[n], s1 = offs[n + 1];
    int deg = s1 - s0;
    float2 acc = {0.f, 0.f};
    int base = 0;
    while (base < deg) {
        int chunk = deg - base;
        if (chunk > 64) chunk = 64;
        int sl = 0;
        if (lane < chunk) sl = slots[s0 + base + lane];
        int j = 0;
        for (; j + 4 <= chunk; j += 4) {
            int c0 = __shfl(sl, j),     c1 = __shfl(sl, j + 1);
            int c2 = __shfl(sl, j + 2), c3 = __shfl(sl, j + 3);
            float2 y0 = ((const float2*)(cell_out + (size_t)c0 * D))[lane];
            float2 y1 = ((const float2*)(cell_out + (size_t)c1 * D))[lane];
            float2 y2 = ((const float2*)(cell_out + (size_t)c2 * D))[lane];
            float2 y3 = ((const float2*)(cell_out + (size_t)c3 * D))[lane];
            acc.x += y0.x + y1.x + y2.x + y3.x;
            acc.y += y0.y + y1.y + y2.y + y3.y;
        }
        for (; j < chunk; ++j) {
            int cc = __shfl(sl, j);
            float2 y = ((const float2*)(cell_out + (size_t)cc * D))[lane];
            acc.x += y.x;
            acc.y += y.y;
        }
        base += chunk;
    }
    float inv = deg ? 1.f / (float)deg : 0.f;
    float2 r; r.x = acc.x * inv; r.y = acc.y * inv;
    ((float2*)(node_out + (size_t)n * D))[lane] = r;
}

// ================= fused gather + 2-layer MLP via bf16x3 MFMA =================
// Block: 32 cells, 256 threads = 4 waves. Wave w owns n-quarter [w*32, w*32+32)
// for BOTH 16-row tiles. X (32x256) staged in LDS as bf16 hi/lo with XOR swizzle.
__device__ __forceinline__ void stage_split(char* lds, int row, int col8, const float* v) {
    unsigned int byte = ((unsigned int)row << 9) + ((unsigned int)col8 << 4);
    byte ^= (unsigned int)(row & 7) << 4;            // G4 swizzle: kill stride-512B conflicts
    uint4 hi, lo;
    unsigned int* hp = (unsigned int*)&hi;
    unsigned int* lp = (unsigned int*)&lo;
    #pragma unroll
    for (int i = 0; i < 4; i++) {
        unsigned int h = cvt_pk_bf16(v[2 * i], v[2 * i + 1]);
        float h0 = __uint_as_float(h << 16);
        float h1 = __uint_as_float(h & 0xffff0000u);
        hp[i] = h;
        lp[i] = cvt_pk_bf16(v[2 * i] - h0, v[2 * i + 1] - h1);
    }
    *(uint4*)(lds + byte)         = hi;              // X-hi: [0, 16K)
    *(uint4*)(lds + 16384 + byte) = lo;              // X-lo: [16K, 32K)
}

__global__ __launch_bounds__(256, 4) void k_mlp(const float* __restrict__ cell_attr,
                                                const float* __restrict__ na,
                                                const int* __restrict__ face,
                                                const u16* __restrict__ w1h,
                                                const u16* __restrict__ w1l,
                                                const u16* __restrict__ w2h,
                                                const u16* __restrict__ w2l,
                                                const float* __restrict__ b1,
                                                const float* __restrict__ b2,
                                                float* __restrict__ out) {
    __shared__ char lds[32768];
    const int t  = threadIdx.x;
    const int c0 = blockIdx.x * 32;

    // ---- stage X = [cell_attr | mean-of-3-nodes] as bf16 hi/lo ----
    {
        const int r = t >> 3;        // 0..31  (cell row within tile)
        const int q = t & 7;         // 0..7   (16-col chunk)
        float v[16];
        const float* pa = cell_attr + (size_t)(c0 + r) * D + q * 16;
        #pragma unroll
        for (int i = 0; i < 4; i++) *(float4*)(v + 4 * i) = *(const float4*)(pa + 4 * i);
        stage_split(lds, r, q * 2,     v);
        stage_split(lds, r, q * 2 + 1, v + 8);

        const int cid = c0 + r;
        const int f0 = face[cid], f1 = face[NC + cid], f2 = face[2 * NC + cid];
        const float* p0 = na + (size_t)f0 * D + q * 16;
        const float* p1 = na + (size_t)f1 * D + q * 16;
        const float* p2 = na + (size_t)f2 * D + q * 16;
        const float third = 1.f / 3.f;
        #pragma unroll
        for (int i = 0; i < 4; i++) {
            float4 a0 = *(const float4*)(p0 + 4 * i);
            float4 a1 = *(const float4*)(p1 + 4 * i);
            float4 a2 = *(const float4*)(p2 + 4 * i);
            v[4 * i + 0] = (a0.x + a1.x + a2.x) * third;
            v[4 * i + 1] = (a0.y + a1.y + a2.y) * third;
            v[4 * i + 2] = (a0.z + a1.z + a2.z) * third;
            v[4 * i + 3] = (a0.w + a1.w + a2.w) * third;
        }
        stage_split(lds, r, 16 + q * 2, v);
        stage_split(lds, r, 17 + q * 2, v + 8);
    }
    __syncthreads();

    const int w  = t >> 6;           // wave 0..3 -> n-quarter
    const int l  = t & 63;
    const int lr = l & 15;           // A row / B-C col within tile
    const int lg = l >> 4;           // k group (8 contiguous k)
    const unsigned int swz = (unsigned int)(lr & 7) << 4;
    const size_t wl8 = (size_t)l * 8;
    const f32x4 z4 = {0.f, 0.f, 0.f, 0.f};
    f32x4 acc[2][2] = {{z4, z4}, {z4, z4}};          // [row-tile][n-tile]

    // ---- GEMM1: X (32x256) @ W1 (256x128), bf16x3 ----
    {
        const unsigned int abase = ((unsigned int)lr << 9) + ((unsigned int)lg << 4);
        const u16* pW1h = w1h + (size_t)(w * 2) * 512 + wl8;
        const u16* pW1l = w1l + (size_t)(w * 2) * 512 + wl8;
        #pragma unroll 2
        for (int kt = 0; kt < 8; ++kt) {
            unsigned int ab = (abase + (unsigned int)kt * 64) ^ swz;
            bf16x8 aH0 = *(const bf16x8*)(lds + ab);
            bf16x8 aL0 = *(const bf16x8*)(lds + 16384 + ab);
            bf16x8 aH1 = *(const bf16x8*)(lds + ab + 8192);          // rows 16..31
            bf16x8 aL1 = *(const bf16x8*)(lds + 16384 + ab + 8192);
            #pragma unroll
            for (int jn = 0; jn < 2; ++jn) {
                size_t fo = (size_t)(kt * 8 + jn) * 512;
                bf16x8 bH = *(const bf16x8*)(pW1h + fo);
                bf16x8 bL = *(const bf16x8*)(pW1l + fo);
                acc[0][jn] = MFMA16(aH0, bL, acc[0][jn]);
                acc[0][jn] = MFMA16(aL0, bH, acc[0][jn]);
                acc[0][jn] = MFMA16(aH0, bH, acc[0][jn]);
                acc[1][jn] = MFMA16(aH1, bL, acc[1][jn]);
                acc[1][jn] = MFMA16(aL1, bH, acc[1][jn]);
                acc[1][jn] = MFMA16(aH1, bH, acc[1][jn]);
            }
        }
    }

    __syncthreads();   // all waves done reading X before H overwrites it

    // ---- bias + relu, re-split H (32x128) into LDS (reuses X-hi region) ----
    {
        const int col0 = w * 32 + lr;          // jn = 0
        const int col1 = col0 + 16;            // jn = 1
        const float bb0 = b1[col0];
        const float bb1 = b1[col1];
        #pragma unroll
        for (int rt = 0; rt < 2; ++rt) {
            #pragma unroll
            for (int r = 0; r < 4; ++r) {
                int row = rt * 16 + lg * 4 + r;       // C/D: row = 4*(lane>>4)+reg
                float h0 = fmaxf(acc[rt][0][r] + bb0, 0.f);
                float h1 = fmaxf(acc[rt][1][r] + bb1, 0.f);
                unsigned int ph = cvt_pk_bf16(h0, h1);
                float f0 = __uint_as_float(ph << 16);
                float f1 = __uint_as_float(ph & 0xffff0000u);
                unsigned int pl = cvt_pk_bf16(h0 - f0, h1 - f1);
                unsigned int swzr = (unsigned int)(row & 7) << 4;
                unsigned int b0 = (((unsigned int)row << 8) + ((unsigned int)col0 << 1)) ^ swzr;
                unsigned int bcol1 = (((unsigned int)row << 8) + ((unsigned int)col1 << 1)) ^ swzr;
                *(u16*)(lds + b0)            = (u16)ph;       // H-hi: [0, 8K)
                *(u16*)(lds + bcol1)         = (u16)(ph >> 16);
                *(u16*)(lds + 8192 + b0)     = (u16)pl;       // H-lo: [8K, 16K)
                *(u16*)(lds + 8192 + bcol1)  = (u16)(pl >> 16);
            }
        }
    }
    __syncthreads();

    // ---- GEMM2: H (32x128) @ W2 (128x128), bf16x3 ----
    f32x4 acc2[2][2] = {{z4, z4}, {z4, z4}};
    {
        const unsigned int abase = ((unsigned int)lr << 8) + ((unsigned int)lg << 4);
        const u16* pW2h = w2h + (size_t)(w * 2) * 512 + wl8;
        const u16* pW2l = w2l + (size_t)(w * 2) * 512 + wl8;
        #pragma unroll 2
        for (int kt = 0; kt < 4; ++kt) {
            unsigned int ab = (abase + (unsigned int)kt * 64) ^ swz;
            bf16x8 aH0 = *(const bf16x8*)(lds + ab);
            bf16x8 aL0 = *(const bf16x8*)(lds + 8192 + ab);
            bf16x8 aH1 = *(const bf16x8*)(lds + ab + 4096);          // rows 16..31
            bf16x8 aL1 = *(const bf16x8*)(lds + 8192 + ab + 4096);
            #pragma unroll
            for (int jn = 0; jn < 2; ++jn) {
                size_t fo = (size_t)(kt * 8 + jn) * 512;
                bf16x8 bH = *(const bf16x8*)(pW2h + fo);
                bf16x8 bL = *(const bf16x8*)(pW2l + fo);
                acc2[0][jn] = MFMA16(aH0, bL, acc2[0][jn]);
                acc2[0][jn] = MFMA16(aL0, bH, acc2[0][jn]);
                acc2[0][jn] = MFMA16(aH0, bH, acc2[0][jn]);
                acc2[1][jn] = MFMA16(aH1, bL, acc2[1][jn]);
                acc2[1][jn] = MFMA16(aL1, bH, acc2[1][jn]);
                acc2[1][jn] = MFMA16(aH1, bH, acc2[1][jn]);
            }
        }
    }

    // ---- bias + store ----
    #pragma unroll
    for (int jn = 0; jn < 2; ++jn) {
        int col = w * 32 + jn * 16 + lr;
        float bb = b2[col];
        #pragma unroll
        for (int rt = 0; rt < 2; ++rt) {
            #pragma unroll
            for (int r = 0; r < 4; ++r) {
                int row = c0 + rt * 16 + lg * 4 + r;
                out[(size_t)row * D + col] = acc2[rt][jn][r] + bb;
            }
        }
    }
}

extern "C" void kernel_launch(void* const* d_in, const int* in_sizes, int n_in,
                              void* d_out, int out_size, void* d_ws, size_t ws_size,
                              hipStream_t stream) {
    (void)in_sizes; (void)n_in; (void)out_size; (void)ws_size;
    const float* cell_attr = (const float*)d_in[0];
    const float* edge_attr = (const float*)d_in[1];
    const float* emb       = (const float*)d_in[2];
    const int*   ei        = (const int*)d_in[3];
    const int*   face      = (const int*)d_in[4];
    const float* W1        = (const float*)d_in[5];
    const float* b1        = (const float*)d_in[6];
    const float* W2        = (const float*)d_in[7];
    const float* b2        = (const float*)d_in[8];

    float* out_cell = (float*)d_out;                    // [C*D]
    float* out_node = out_cell + (size_t)NC * D;        // [N*D] (node_agg scratch, then final)

    // ws layout (4B units)
    float* denom  = (float*)d_ws;                 // [N]
    int*   cntA   = (int*)d_ws + NN;              // [N]
    int*   cntF   = cntA + NN;                    // [N]
    int*   curA   = cntF + NN;                    // [N]
    int*   curF   = curA + NN;                    // [N]
    float* expv   = (float*)(curF + NN);          // [2E]
    int*   offA   = (int*)(expv + 2 * NE);        // [N+1]
    int*   offF   = offA + NN + 1;                // [N+1]
    int*   bsumA  = offF + NN + 1;                // [512]
    int*   bsumF  = bsumA + 512;                  // [512]
    int*   slotsF = bsumF + 512;                  // [3C]
    int2*  swA    = (int2*)(((uintptr_t)(slotsF + 3 * NC) + 7) & ~(uintptr_t)7);  // [2E] pairs
    // W fragment arrays (16B-aligned): 192 KB
    u16* w1h = (u16*)(((uintptr_t)(swA + 2 * NE) + 15) & ~(uintptr_t)15);
    u16* w1l = w1h + 64 * 512;
    u16* w2h = w1l + 64 * 512;                    // 32 frags * 512 u16
    u16* w2l = w2h + 32 * 512;

    hipMemsetAsync(d_ws, 0, (size_t)5 * NN * 4, stream);   // denom, cntA, cntF, curA, curF

    k_att_prep<<<ATT_B + 2 * HB + 24, 256, 0, stream>>>(edge_attr, emb, ei, face, expv, denom,
                                                        cntA, cntF, W1, W2, w1h, w1l, w2h, w2l);

    k_scan_blocks<<<2 * NB, 256, 0, stream>>>(cntA, cntF, bsumA, bsumF);
    k_scan_top   <<<2, 512, 0, stream>>>(bsumA, bsumF, NB);
    k_scan_final <<<2 * NB, 256, 0, stream>>>(cntA, cntF, bsumA, bsumF, offA, offF);

    k_fill<<<2 * HB, 256, 0, stream>>>(ei, expv, face, offA, offF, curA, curF, swA, slotsF);

    k_agg_gather<<<(NN + 3) / 4, 256, 0, stream>>>(edge_attr, swA, denom, offA, out_node);

    k_mlp<<<NC / 32, 256, 0, stream>>>(cell_attr, out_node, face,
                                       w1h, w1l, w2h, w2l, b1, b2, out_cell);

    k_smean_gather<<<(NN + 3) / 4, 256, 0, stream>>>(out_cell, offF, slotsF, out_node);
}

// Round 4
// 658.083 us; speedup vs baseline: 1.4560x; 1.0118x over previous
//
#include <hip/hip_runtime.h>

#define NN 100000   // nodes
#define NC 200000   // cells
#define NE 300000   // edges
#define D  128
#define NB 391      // scan blocks = ceil(NN/256)
#define ATT_B 2048  // persistent attention blocks (grid-stride)
#define HB 2344     // hist blocks = ceil(2E/256) = ceil(3C/256)

typedef unsigned short u16;
typedef __attribute__((ext_vector_type(8))) short bf16x8;  // 8 bf16 = 4 VGPRs
typedef __attribute__((ext_vector_type(4))) float f32x4;   // MFMA accumulator

__device__ __forceinline__ u16 f2bf(float x) {            // fp32 -> bf16 (RNE)
    unsigned int u = __float_as_uint(x);
    u += 0x7fffu + ((u >> 16) & 1u);
    return (u16)(u >> 16);
}
__device__ __forceinline__ float bf2f(u16 h) {
    return __uint_as_float((unsigned int)h << 16);
}
// packed f32x2 -> bf16x2 (low16 = a, high16 = b); no builtin on gfx950
__device__ __forceinline__ unsigned int cvt_pk_bf16(float a, float b) {
    unsigned int r;
    asm("v_cvt_pk_bf16_f32 %0, %1, %2" : "=v"(r) : "v"(a), "v"(b));
    return r;
}

#define MFMA16(a, b, c) __builtin_amdgcn_mfma_f32_16x16x32_bf16((a), (b), (c), 0, 0, 0)

// ====== attention logits (grid-stride, 2-deep) + inlined cntA histogram ======
// No denom atomics: softmax denominator is summed later in k_agg_gather.
__global__ __launch_bounds__(256) void k_att(const float* __restrict__ edge_attr,
                                             const float* __restrict__ emb,
                                             const int* __restrict__ ei,
                                             float* __restrict__ expv,
                                             int* __restrict__ cntA) {
    const int HW = ATT_B * 8;              // total half-waves
    int hw  = blockIdx.x * 8 + (threadIdx.x >> 5);
    int sub = threadIdx.x & 31;
    const float inv_scale = 0.08838834764831845f; // 1/sqrt(128)
    for (int e0 = hw; e0 < NE; e0 += 2 * HW) {
        int e1 = e0 + HW;
        bool h1 = (e1 < NE);
        int sd0 = ei[e0], rc0 = ei[NE + e0];
        int sd1 = h1 ? ei[e1] : 0;
        int rc1 = h1 ? ei[NE + e1] : 0;
        float4 a0 = ((const float4*)(edge_attr + (size_t)e0 * D))[sub];
        float4 r0 = ((const float4*)(emb + (size_t)rc0 * D))[sub];
        float4 s0 = ((const float4*)(emb + (size_t)sd0 * D))[sub];
        float dr0 = a0.x * r0.x + a0.y * r0.y + a0.z * r0.z + a0.w * r0.w;
        float ds0 = a0.x * s0.x + a0.y * s0.y + a0.z * s0.z + a0.w * s0.w;
        float dr1 = 0.f, ds1 = 0.f;
        if (h1) {
            float4 a1 = ((const float4*)(edge_attr + (size_t)e1 * D))[sub];
            float4 r1 = ((const float4*)(emb + (size_t)rc1 * D))[sub];
            float4 s1 = ((const float4*)(emb + (size_t)sd1 * D))[sub];
            dr1 = a1.x * r1.x + a1.y * r1.y + a1.z * r1.z + a1.w * r1.w;
            ds1 = a1.x * s1.x + a1.y * s1.y + a1.z * s1.z + a1.w * s1.w;
        }
        #pragma unroll
        for (int off = 16; off > 0; off >>= 1) {
            dr0 += __shfl_xor(dr0, off);
            ds0 += __shfl_xor(ds0, off);
            dr1 += __shfl_xor(dr1, off);
            ds1 += __shfl_xor(ds1, off);
        }
        if (sub == 0) {
            expv[e0]      = __expf(dr0 * inv_scale);
            expv[NE + e0] = __expf(ds0 * inv_scale);
            atomicAdd(&cntA[rc0], 1);
            atomicAdd(&cntA[sd0], 1);
            if (h1) {
                expv[e1]      = __expf(dr1 * inv_scale);
                expv[NE + e1] = __expf(ds1 * inv_scale);
                atomicAdd(&cntA[rc1], 1);
                atomicAdd(&cntA[sd1], 1);
            }
        }
    }
}

// ====== face histogram + W prepack (fragment-major bf16 hi/lo split) ======
__global__ __launch_bounds__(256) void k_prep_face_w(const int* __restrict__ face,
                                                     int* __restrict__ cntF,
                                                     const float* __restrict__ W1,
                                                     const float* __restrict__ W2,
                                                     u16* __restrict__ w1h, u16* __restrict__ w1l,
                                                     u16* __restrict__ w2h, u16* __restrict__ w2l) {
    int b = blockIdx.x;
    int t = threadIdx.x;
    if (b < HB) {
        int i = b * 256 + t;
        if (i >= 3 * NC) return;
        atomicAdd(&cntF[face[i]], 1);
    } else {
        int tid = (b - HB) * 256 + t;
        if (tid >= 6144) return;                 // 64 W1 frags + 32 W2 frags, 64 lanes each
        int l = tid & 63;
        int f = tid >> 6;
        const float* W; u16 *oh, *ol; int fi;
        if (f < 64) { W = W1; oh = w1h; ol = w1l; fi = f; }
        else        { W = W2; oh = w2h; ol = w2l; fi = f - 64; }
        int kt = fi >> 3, nt = fi & 7;
        int k0 = kt * 32 + 8 * (l >> 4);
        int n  = nt * 16 + (l & 15);
        #pragma unroll
        for (int i = 0; i < 8; i++) {
            float x = W[(size_t)(k0 + i) * 128 + n];
            u16 h = f2bf(x);
            oh[(size_t)fi * 512 + l * 8 + i] = h;
            ol[(size_t)fi * 512 + l * 8 + i] = f2bf(x - bf2f(h));
        }
    }
}

// ================= CSR scan (both arrays in one grid) =================
__global__ __launch_bounds__(256) void k_scan_blocks(const int* __restrict__ cntA,
                                                     const int* __restrict__ cntF,
                                                     int* __restrict__ bsumA,
                                                     int* __restrict__ bsumF) {
    __shared__ int s[256];
    int bb = blockIdx.x;
    bool fa = bb >= NB;
    const int* cnt = fa ? cntF : cntA;
    int* bsum = fa ? bsumF : bsumA;
    int blk = fa ? bb - NB : bb;
    int t = threadIdx.x;
    int i = blk * 256 + t;
    s[t] = (i < NN) ? cnt[i] : 0;
    __syncthreads();
    #pragma unroll
    for (int off = 128; off > 0; off >>= 1) {
        if (t < off) s[t] += s[t + off];
        __syncthreads();
    }
    if (t == 0) bsum[blk] = s[0];
}

__global__ __launch_bounds__(512) void k_scan_top(int* __restrict__ bsumA,
                                                  int* __restrict__ bsumF, int nb) {
    __shared__ int s[512];
    int* bsum = blockIdx.x ? bsumF : bsumA;
    int t = threadIdx.x;
    int v = (t < nb) ? bsum[t] : 0;
    s[t] = v;
    __syncthreads();
    #pragma unroll
    for (int off = 1; off < 512; off <<= 1) {
        int x = (t >= off) ? s[t - off] : 0;
        __syncthreads();
        s[t] += x;
        __syncthreads();
    }
    if (t < nb) bsum[t] = s[t] - v;   // exclusive
}

__global__ __launch_bounds__(256) void k_scan_final(const int* __restrict__ cntA,
                                                    const int* __restrict__ cntF,
                                                    const int* __restrict__ bsumA,
                                                    const int* __restrict__ bsumF,
                                                    int* __restrict__ offA,
                                                    int* __restrict__ offF) {
    __shared__ int s[256];
    int bb = blockIdx.x;
    bool fa = bb >= NB;
    const int* cnt = fa ? cntF : cntA;
    const int* bsum = fa ? bsumF : bsumA;
    int* off_out = fa ? offF : offA;
    int total = fa ? 3 * NC : 2 * NE;
    int blk = fa ? bb - NB : bb;
    int t = threadIdx.x;
    int i = blk * 256 + t;
    int v = (i < NN) ? cnt[i] : 0;
    s[t] = v;
    __syncthreads();
    #pragma unroll
    for (int off = 1; off < 256; off <<= 1) {
        int x = (t >= off) ? s[t - off] : 0;
        __syncthreads();
        s[t] += x;
        __syncthreads();
    }
    if (i < NN) off_out[i] = s[t] - v + bsum[blk];
    if (i == 0) off_out[NN] = total;
}

// ===== fill (att slot+weight packed as int2, face slots) =====
__global__ __launch_bounds__(256) void k_fill(const int* __restrict__ ei,
                                              const float* __restrict__ expv,
                                              const int* __restrict__ face,
                                              const int* __restrict__ offA,
                                              const int* __restrict__ offF,
                                              int* __restrict__ curA,
                                              int* __restrict__ curF,
                                              int2* __restrict__ swA,
                                              int* __restrict__ slotsF) {
    int b = blockIdx.x;
    int t = threadIdx.x;
    if (b < HB) {
        int i = b * 256 + t;
        if (i >= 2 * NE) return;
        int tgt = (i < NE) ? ei[NE + i] : ei[i - NE];
        int pos = offA[tgt] + atomicAdd(&curA[tgt], 1);
        int2 p;
        p.x = (i < NE) ? i : i - NE;              // edge row
        p.y = __float_as_int(expv[i]);            // weight
        swA[pos] = p;
    } else {
        int i = (b - HB) * 256 + t;
        if (i >= 3 * NC) return;
        int tgt = face[i];
        int pos = offF[tgt] + atomicAdd(&curF[tgt], 1);
        int c = i; if (c >= NC) c -= NC; if (c >= NC) c -= NC;   // cell id = i mod NC
        slotsF[pos] = c;
    }
}

// ===== node aggregation: register-batched gathers + in-loop denom sum =====
__global__ __launch_bounds__(256) void k_agg_gather(const float* __restrict__ edge_attr,
                                                    const int2* __restrict__ swA,
                                                    const int* __restrict__ offs,
                                                    float* __restrict__ na) {
    int n = blockIdx.x * 4 + (threadIdx.x >> 6);
    int lane = threadIdx.x & 63;
    if (n >= NN) return;
    int s0 = offs[n], s1 = offs[n + 1];
    int deg = s1 - s0;
    float2 acc = {0.f, 0.f};
    float wsum = 0.f;
    int base = 0;
    while (base < deg) {
        int chunk = deg - base;
        if (chunk > 64) chunk = 64;
        int sl = 0; float wl = 0.f;
        if (lane < chunk) {
            int2 p = swA[s0 + base + lane];
            sl = p.x;
            wl = __int_as_float(p.y);
        }
        wsum += wl;                               // own slot's weight only
        int j = 0;
        for (; j + 4 <= chunk; j += 4) {
            int r0 = __shfl(sl, j),     r1 = __shfl(sl, j + 1);
            int r2 = __shfl(sl, j + 2), r3 = __shfl(sl, j + 3);
            float w0 = __shfl(wl, j),     w1 = __shfl(wl, j + 1);
            float w2 = __shfl(wl, j + 2), w3 = __shfl(wl, j + 3);
            float2 a0 = ((const float2*)(edge_attr + (size_t)r0 * D))[lane];
            float2 a1 = ((const float2*)(edge_attr + (size_t)r1 * D))[lane];
            float2 a2 = ((const float2*)(edge_attr + (size_t)r2 * D))[lane];
            float2 a3 = ((const float2*)(edge_attr + (size_t)r3 * D))[lane];
            acc.x += w0 * a0.x + w1 * a1.x + w2 * a2.x + w3 * a3.x;
            acc.y += w0 * a0.y + w1 * a1.y + w2 * a2.y + w3 * a3.y;
        }
        for (; j < chunk; ++j) {
            int rr = __shfl(sl, j);
            float ww = __shfl(wl, j);
            float2 a = ((const float2*)(edge_attr + (size_t)rr * D))[lane];
            acc.x += ww * a.x;
            acc.y += ww * a.y;
        }
        base += chunk;
    }
    #pragma unroll
    for (int off = 32; off > 0; off >>= 1) wsum += __shfl_xor(wsum, off);
    float inv = (deg > 0) ? 1.f / wsum : 0.f;
    float2 r; r.x = acc.x * inv; r.y = acc.y * inv;
    ((float2*)(na + (size_t)n * D))[lane] = r;
}

// ===== scatter-mean: register-batched gathers, full wave per node =====
__global__ __launch_bounds__(256) void k_smean_gather(const float* __restrict__ cell_out,
                                                      const int* __restrict__ offs,
                                                      const int* __restrict__ slots,
                                                      float* __restrict__ node_out) {
    int n = blockIdx.x * 4 + (threadIdx.x >> 6);
    int lane = threadIdx.x & 63;
    if (n >= NN) return;
    int s0 = offs[n], s1 = offs[n + 1];
    int deg = s1 - s0;
    float2 acc = {0.f, 0.f};
    int base = 0;
    while (base < deg) {
        int chunk = deg - base;
        if (chunk > 64) chunk = 64;
        int sl = 0;
        if (lane < chunk) sl = slots[s0 + base + lane];
        int j = 0;
        for (; j + 4 <= chunk; j += 4) {
            int c0 = __shfl(sl, j),     c1 = __shfl(sl, j + 1);
            int c2 = __shfl(sl, j + 2), c3 = __shfl(sl, j + 3);
            float2 y0 = ((const float2*)(cell_out + (size_t)c0 * D))[lane];
            float2 y1 = ((const float2*)(cell_out + (size_t)c1 * D))[lane];
            float2 y2 = ((const float2*)(cell_out + (size_t)c2 * D))[lane];
            float2 y3 = ((const float2*)(cell_out + (size_t)c3 * D))[lane];
            acc.x += y0.x + y1.x + y2.x + y3.x;
            acc.y += y0.y + y1.y + y2.y + y3.y;
        }
        for (; j < chunk; ++j) {
            int cc = __shfl(sl, j);
            float2 y = ((const float2*)(cell_out + (size_t)cc * D))[lane];
            acc.x += y.x;
            acc.y += y.y;
        }
        base += chunk;
    }
    int degc = s1 - s0;
    float inv = degc ? 1.f / (float)degc : 0.f;
    float2 r; r.x = acc.x * inv; r.y = acc.y * inv;
    ((float2*)(node_out + (size_t)n * D))[lane] = r;
}

// ================= fused gather + 2-layer MLP via bf16x3 MFMA =================
// Block: 32 cells, 256 threads = 4 waves. Wave w owns n-quarter [w*32, w*32+32)
// for BOTH 16-row tiles. X (32x256) staged in LDS as bf16 hi/lo with XOR swizzle.
__device__ __forceinline__ void stage_split(char* lds, int row, int col8, const float* v) {
    unsigned int byte = ((unsigned int)row << 9) + ((unsigned int)col8 << 4);
    byte ^= (unsigned int)(row & 7) << 4;            // G4 swizzle: kill stride-512B conflicts
    uint4 hi, lo;
    unsigned int* hp = (unsigned int*)&hi;
    unsigned int* lp = (unsigned int*)&lo;
    #pragma unroll
    for (int i = 0; i < 4; i++) {
        unsigned int h = cvt_pk_bf16(v[2 * i], v[2 * i + 1]);
        float h0 = __uint_as_float(h << 16);
        float h1 = __uint_as_float(h & 0xffff0000u);
        hp[i] = h;
        lp[i] = cvt_pk_bf16(v[2 * i] - h0, v[2 * i + 1] - h1);
    }
    *(uint4*)(lds + byte)         = hi;              // X-hi: [0, 16K)
    *(uint4*)(lds + 16384 + byte) = lo;              // X-lo: [16K, 32K)
}

__global__ __launch_bounds__(256, 4) void k_mlp(const float* __restrict__ cell_attr,
                                                const float* __restrict__ na,
                                                const int* __restrict__ face,
                                                const u16* __restrict__ w1h,
                                                const u16* __restrict__ w1l,
                                                const u16* __restrict__ w2h,
                                                const u16* __restrict__ w2l,
                                                const float* __restrict__ b1,
                                                const float* __restrict__ b2,
                                                float* __restrict__ out) {
    __shared__ char lds[32768];
    const int t  = threadIdx.x;
    const int c0 = blockIdx.x * 32;

    // ---- stage X = [cell_attr | mean-of-3-nodes] as bf16 hi/lo ----
    {
        const int r = t >> 3;        // 0..31  (cell row within tile)
        const int q = t & 7;         // 0..7   (16-col chunk)
        float v[16];
        const float* pa = cell_attr + (size_t)(c0 + r) * D + q * 16;
        #pragma unroll
        for (int i = 0; i < 4; i++) *(float4*)(v + 4 * i) = *(const float4*)(pa + 4 * i);
        stage_split(lds, r, q * 2,     v);
        stage_split(lds, r, q * 2 + 1, v + 8);

        const int cid = c0 + r;
        const int f0 = face[cid], f1 = face[NC + cid], f2 = face[2 * NC + cid];
        const float* p0 = na + (size_t)f0 * D + q * 16;
        const float* p1 = na + (size_t)f1 * D + q * 16;
        const float* p2 = na + (size_t)f2 * D + q * 16;
        const float third = 1.f / 3.f;
        #pragma unroll
        for (int i = 0; i < 4; i++) {
            float4 a0 = *(const float4*)(p0 + 4 * i);
            float4 a1 = *(const float4*)(p1 + 4 * i);
            float4 a2 = *(const float4*)(p2 + 4 * i);
            v[4 * i + 0] = (a0.x + a1.x + a2.x) * third;
            v[4 * i + 1] = (a0.y + a1.y + a2.y) * third;
            v[4 * i + 2] = (a0.z + a1.z + a2.z) * third;
            v[4 * i + 3] = (a0.w + a1.w + a2.w) * third;
        }
        stage_split(lds, r, 16 + q * 2, v);
        stage_split(lds, r, 17 + q * 2, v + 8);
    }
    __syncthreads();

    const int w  = t >> 6;           // wave 0..3 -> n-quarter
    const int l  = t & 63;
    const int lr = l & 15;           // A row / B-C col within tile
    const int lg = l >> 4;           // k group (8 contiguous k)
    const unsigned int swz = (unsigned int)(lr & 7) << 4;
    const size_t wl8 = (size_t)l * 8;
    const f32x4 z4 = {0.f, 0.f, 0.f, 0.f};
    f32x4 acc[2][2] = {{z4, z4}, {z4, z4}};          // [row-tile][n-tile]

    // ---- GEMM1: X (32x256) @ W1 (256x128), bf16x3 ----
    {
        const unsigned int abase = ((unsigned int)lr << 9) + ((unsigned int)lg << 4);
        const u16* pW1h = w1h + (size_t)(w * 2) * 512 + wl8;
        const u16* pW1l = w1l + (size_t)(w * 2) * 512 + wl8;
        #pragma unroll 2
        for (int kt = 0; kt < 8; ++kt) {
            unsigned int ab = (abase + (unsigned int)kt * 64) ^ swz;
            bf16x8 aH0 = *(const bf16x8*)(lds + ab);
            bf16x8 aL0 = *(const bf16x8*)(lds + 16384 + ab);
            bf16x8 aH1 = *(const bf16x8*)(lds + ab + 8192);          // rows 16..31
            bf16x8 aL1 = *(const bf16x8*)(lds + 16384 + ab + 8192);
            #pragma unroll
            for (int jn = 0; jn < 2; ++jn) {
                size_t fo = (size_t)(kt * 8 + jn) * 512;
                bf16x8 bH = *(const bf16x8*)(pW1h + fo);
                bf16x8 bL = *(const bf16x8*)(pW1l + fo);
                acc[0][jn] = MFMA16(aH0, bL, acc[0][jn]);
                acc[0][jn] = MFMA16(aL0, bH, acc[0][jn]);
                acc[0][jn] = MFMA16(aH0, bH, acc[0][jn]);
                acc[1][jn] = MFMA16(aH1, bL, acc[1][jn]);
                acc[1][jn] = MFMA16(aL1, bH, acc[1][jn]);
                acc[1][jn] = MFMA16(aH1, bH, acc[1][jn]);
            }
        }
    }

    __syncthreads();   // all waves done reading X before H overwrites it

    // ---- bias + relu, re-split H (32x128) into LDS (reuses X-hi region) ----
    {
        const int col0 = w * 32 + lr;          // jn = 0
        const int col1 = col0 + 16;            // jn = 1
        const float bb0 = b1[col0];
        const float bb1 = b1[col1];
        #pragma unroll
        for (int rt = 0; rt < 2; ++rt) {
            #pragma unroll
            for (int r = 0; r < 4; ++r) {
                int row = rt * 16 + lg * 4 + r;       // C/D: row = 4*(lane>>4)+reg
                float h0 = fmaxf(acc[rt][0][r] + bb0, 0.f);
                float h1 = fmaxf(acc[rt][1][r] + bb1, 0.f);
                unsigned int ph = cvt_pk_bf16(h0, h1);
                float f0 = __uint_as_float(ph << 16);
                float f1 = __uint_as_float(ph & 0xffff0000u);
                unsigned int pl = cvt_pk_bf16(h0 - f0, h1 - f1);
                unsigned int swzr = (unsigned int)(row & 7) << 4;
                unsigned int b0 = (((unsigned int)row << 8) + ((unsigned int)col0 << 1)) ^ swzr;
                unsigned int bcol1 = (((unsigned int)row << 8) + ((unsigned int)col1 << 1)) ^ swzr;
                *(u16*)(lds + b0)            = (u16)ph;       // H-hi: [0, 8K)
                *(u16*)(lds + bcol1)         = (u16)(ph >> 16);
                *(u16*)(lds + 8192 + b0)     = (u16)pl;       // H-lo: [8K, 16K)
                *(u16*)(lds + 8192 + bcol1)  = (u16)(pl >> 16);
            }
        }
    }
    __syncthreads();

    // ---- GEMM2: H (32x128) @ W2 (128x128), bf16x3 ----
    f32x4 acc2[2][2] = {{z4, z4}, {z4, z4}};
    {
        const unsigned int abase = ((unsigned int)lr << 8) + ((unsigned int)lg << 4);
        const u16* pW2h = w2h + (size_t)(w * 2) * 512 + wl8;
        const u16* pW2l = w2l + (size_t)(w * 2) * 512 + wl8;
        #pragma unroll 2
        for (int kt = 0; kt < 4; ++kt) {
            unsigned int ab = (abase + (unsigned int)kt * 64) ^ swz;
            bf16x8 aH0 = *(const bf16x8*)(lds + ab);
            bf16x8 aL0 = *(const bf16x8*)(lds + 8192 + ab);
            bf16x8 aH1 = *(const bf16x8*)(lds + ab + 4096);          // rows 16..31
            bf16x8 aL1 = *(const bf16x8*)(lds + 8192 + ab + 4096);
            #pragma unroll
            for (int jn = 0; jn < 2; ++jn) {
                size_t fo = (size_t)(kt * 8 + jn) * 512;
                bf16x8 bH = *(const bf16x8*)(pW2h + fo);
                bf16x8 bL = *(const bf16x8*)(pW2l + fo);
                acc2[0][jn] = MFMA16(aH0, bL, acc2[0][jn]);
                acc2[0][jn] = MFMA16(aL0, bH, acc2[0][jn]);
                acc2[0][jn] = MFMA16(aH0, bH, acc2[0][jn]);
                acc2[1][jn] = MFMA16(aH1, bL, acc2[1][jn]);
                acc2[1][jn] = MFMA16(aL1, bH, acc2[1][jn]);
                acc2[1][jn] = MFMA16(aH1, bH, acc2[1][jn]);
            }
        }
    }

    // ---- bias + store ----
    #pragma unroll
    for (int jn = 0; jn < 2; ++jn) {
        int col = w * 32 + jn * 16 + lr;
        float bb = b2[col];
        #pragma unroll
        for (int rt = 0; rt < 2; ++rt) {
            #pragma unroll
            for (int r = 0; r < 4; ++r) {
                int row = c0 + rt * 16 + lg * 4 + r;
                out[(size_t)row * D + col] = acc2[rt][jn][r] + bb;
            }
        }
    }
}

extern "C" void kernel_launch(void* const* d_in, const int* in_sizes, int n_in,
                              void* d_out, int out_size, void* d_ws, size_t ws_size,
                              hipStream_t stream) {
    (void)in_sizes; (void)n_in; (void)out_size; (void)ws_size;
    const float* cell_attr = (const float*)d_in[0];
    const float* edge_attr = (const float*)d_in[1];
    const float* emb       = (const float*)d_in[2];
    const int*   ei        = (const int*)d_in[3];
    const int*   face      = (const int*)d_in[4];
    const float* W1        = (const float*)d_in[5];
    const float* b1        = (const float*)d_in[6];
    const float* W2        = (const float*)d_in[7];
    const float* b2        = (const float*)d_in[8];

    float* out_cell = (float*)d_out;                    // [C*D]
    float* out_node = out_cell + (size_t)NC * D;        // [N*D] (node_agg scratch, then final)

    // ws layout (4B units) — zeroed arrays first
    int*   cntA   = (int*)d_ws;                   // [N]
    int*   cntF   = cntA + NN;                    // [N]
    int*   curA   = cntF + NN;                    // [N]
    int*   curF   = curA + NN;                    // [N]
    float* expv   = (float*)(curF + NN);          // [2E]
    int*   offA   = (int*)(expv + 2 * NE);        // [N+1]
    int*   offF   = offA + NN + 1;                // [N+1]
    int*   bsumA  = offF + NN + 1;                // [512]
    int*   bsumF  = bsumA + 512;                  // [512]
    int*   slotsF = bsumF + 512;                  // [3C]
    int2*  swA    = (int2*)(((uintptr_t)(slotsF + 3 * NC) + 7) & ~(uintptr_t)7);  // [2E] pairs
    // W fragment arrays (16B-aligned): 192 KB
    u16* w1h = (u16*)(((uintptr_t)(swA + 2 * NE) + 15) & ~(uintptr_t)15);
    u16* w1l = w1h + 64 * 512;
    u16* w2h = w1l + 64 * 512;                    // 32 frags * 512 u16
    u16* w2l = w2h + 32 * 512;

    hipMemsetAsync(d_ws, 0, (size_t)4 * NN * 4, stream);   // cntA, cntF, curA, curF

    k_att<<<ATT_B, 256, 0, stream>>>(edge_attr, emb, ei, expv, cntA);

    k_prep_face_w<<<HB + 24, 256, 0, stream>>>(face, cntF, W1, W2, w1h, w1l, w2h, w2l);

    k_scan_blocks<<<2 * NB, 256, 0, stream>>>(cntA, cntF, bsumA, bsumF);
    k_scan_top   <<<2, 512, 0, stream>>>(bsumA, bsumF, NB);
    k_scan_final <<<2 * NB, 256, 0, stream>>>(cntA, cntF, bsumA, bsumF, offA, offF);

    k_fill<<<2 * HB, 256, 0, stream>>>(ei, expv, face, offA, offF, curA, curF, swA, slotsF);

    k_agg_gather<<<(NN + 3) / 4, 256, 0, stream>>>(edge_attr, swA, offA, out_node);

    k_mlp<<<NC / 32, 256, 0, stream>>>(cell_attr, out_node, face,
                                       w1h, w1l, w2h, w2l, b1, b2, out_cell);

    k_smean_gather<<<(NN + 3) / 4, 256, 0, stream>>>(out_cell, offF, slotsF, out_node);
}

// Round 5
// 639.556 us; speedup vs baseline: 1.4982x; 1.0290x over previous
//
#include <hip/hip_runtime.h>

#define NN 100000   // nodes
#define NC 200000   // cells
#define NE 300000   // edges
#define D  128
#define NB 391      // scan blocks = ceil(NN/256)
#define HB 2344     // hist blocks = ceil(2E/256) = ceil(3C/256)

typedef unsigned short u16;
typedef __attribute__((ext_vector_type(8))) short bf16x8;  // 8 bf16 = 4 VGPRs
typedef __attribute__((ext_vector_type(4))) float f32x4;   // MFMA accumulator

__device__ __forceinline__ u16 f2bf(float x) {            // fp32 -> bf16 (RNE)
    unsigned int u = __float_as_uint(x);
    u += 0x7fffu + ((u >> 16) & 1u);
    return (u16)(u >> 16);
}
__device__ __forceinline__ float bf2f(u16 h) {
    return __uint_as_float((unsigned int)h << 16);
}
// packed f32x2 -> bf16x2 (low16 = a, high16 = b); no builtin on gfx950
__device__ __forceinline__ unsigned int cvt_pk_bf16(float a, float b) {
    unsigned int r;
    asm("v_cvt_pk_bf16_f32 %0, %1, %2" : "=v"(r) : "v"(a), "v"(b));
    return r;
}

#define MFMA16(a, b, c) __builtin_amdgcn_mfma_f32_16x16x32_bf16((a), (b), (c), 0, 0, 0)

// ====== histograms (edge targets + faces) + W prepack, one launch ======
__global__ __launch_bounds__(256) void k_hist_w(const int* __restrict__ ei,
                                                const int* __restrict__ face,
                                                int* __restrict__ cntA,
                                                int* __restrict__ cntF,
                                                const float* __restrict__ W1,
                                                const float* __restrict__ W2,
                                                u16* __restrict__ w1h, u16* __restrict__ w1l,
                                                u16* __restrict__ w2h, u16* __restrict__ w2l) {
    int b = blockIdx.x;
    int t = threadIdx.x;
    if (b < HB) {
        int i = b * 256 + t;
        if (i >= 2 * NE) return;
        int tgt = (i < NE) ? ei[NE + i] : ei[i - NE];
        atomicAdd(&cntA[tgt], 1);
    } else if (b < 2 * HB) {
        int i = (b - HB) * 256 + t;
        if (i >= 3 * NC) return;
        atomicAdd(&cntF[face[i]], 1);
    } else {
        int tid = (b - 2 * HB) * 256 + t;
        if (tid >= 6144) return;                 // 64 W1 frags + 32 W2 frags, 64 lanes each
        int l = tid & 63;
        int f = tid >> 6;
        const float* W; u16 *oh, *ol; int fi;
        if (f < 64) { W = W1; oh = w1h; ol = w1l; fi = f; }
        else        { W = W2; oh = w2h; ol = w2l; fi = f - 64; }
        int kt = fi >> 3, nt = fi & 7;
        int k0 = kt * 32 + 8 * (l >> 4);
        int n  = nt * 16 + (l & 15);
        #pragma unroll
        for (int i = 0; i < 8; i++) {
            float x = W[(size_t)(k0 + i) * 128 + n];
            u16 h = f2bf(x);
            oh[(size_t)fi * 512 + l * 8 + i] = h;
            ol[(size_t)fi * 512 + l * 8 + i] = f2bf(x - bf2f(h));
        }
    }
}

// ================= CSR scan (both arrays in one grid) =================
__global__ __launch_bounds__(256) void k_scan_blocks(const int* __restrict__ cntA,
                                                     const int* __restrict__ cntF,
                                                     int* __restrict__ bsumA,
                                                     int* __restrict__ bsumF) {
    __shared__ int s[256];
    int bb = blockIdx.x;
    bool fa = bb >= NB;
    const int* cnt = fa ? cntF : cntA;
    int* bsum = fa ? bsumF : bsumA;
    int blk = fa ? bb - NB : bb;
    int t = threadIdx.x;
    int i = blk * 256 + t;
    s[t] = (i < NN) ? cnt[i] : 0;
    __syncthreads();
    #pragma unroll
    for (int off = 128; off > 0; off >>= 1) {
        if (t < off) s[t] += s[t + off];
        __syncthreads();
    }
    if (t == 0) bsum[blk] = s[0];
}

__global__ __launch_bounds__(512) void k_scan_top(int* __restrict__ bsumA,
                                                  int* __restrict__ bsumF, int nb) {
    __shared__ int s[512];
    int* bsum = blockIdx.x ? bsumF : bsumA;
    int t = threadIdx.x;
    int v = (t < nb) ? bsum[t] : 0;
    s[t] = v;
    __syncthreads();
    #pragma unroll
    for (int off = 1; off < 512; off <<= 1) {
        int x = (t >= off) ? s[t - off] : 0;
        __syncthreads();
        s[t] += x;
        __syncthreads();
    }
    if (t < nb) bsum[t] = s[t] - v;   // exclusive
}

__global__ __launch_bounds__(256) void k_scan_final(const int* __restrict__ cntA,
                                                    const int* __restrict__ cntF,
                                                    const int* __restrict__ bsumA,
                                                    const int* __restrict__ bsumF,
                                                    int* __restrict__ offA,
                                                    int* __restrict__ offF) {
    __shared__ int s[256];
    int bb = blockIdx.x;
    bool fa = bb >= NB;
    const int* cnt = fa ? cntF : cntA;
    const int* bsum = fa ? bsumF : bsumA;
    int* off_out = fa ? offF : offA;
    int total = fa ? 3 * NC : 2 * NE;
    int blk = fa ? bb - NB : bb;
    int t = threadIdx.x;
    int i = blk * 256 + t;
    int v = (i < NN) ? cnt[i] : 0;
    s[t] = v;
    __syncthreads();
    #pragma unroll
    for (int off = 1; off < 256; off <<= 1) {
        int x = (t >= off) ? s[t - off] : 0;
        __syncthreads();
        s[t] += x;
        __syncthreads();
    }
    if (i < NN) off_out[i] = s[t] - v + bsum[blk];
    if (i == 0) off_out[NN] = total;
}

// ===== fill (edge-row slots, face slots) =====
__global__ __launch_bounds__(256) void k_fill(const int* __restrict__ ei,
                                              const int* __restrict__ face,
                                              const int* __restrict__ offA,
                                              const int* __restrict__ offF,
                                              int* __restrict__ curA,
                                              int* __restrict__ curF,
                                              int* __restrict__ slotsA,
                                              int* __restrict__ slotsF) {
    int b = blockIdx.x;
    int t = threadIdx.x;
    if (b < HB) {
        int i = b * 256 + t;
        if (i >= 2 * NE) return;
        int tgt = (i < NE) ? ei[NE + i] : ei[i - NE];
        int pos = offA[tgt] + atomicAdd(&curA[tgt], 1);
        slotsA[pos] = (i < NE) ? i : i - NE;      // edge row in [0, NE)
    } else {
        int i = (b - HB) * 256 + t;
        if (i >= 3 * NC) return;
        int tgt = face[i];
        int pos = offF[tgt] + atomicAdd(&curF[tgt], 1);
        int c = i; if (c >= NC) c -= NC; if (c >= NC) c -= NC;   // cell id = i mod NC
        slotsF[pos] = c;
    }
}

// ===== fused attention + aggregation: per node, one emb row reused for all slots =====
// w_slot = exp(dot(edge_attr[row], emb[n]) / sqrt(D));  na[n] = sum(w*ea) / sum(w)
__global__ __launch_bounds__(256) void k_agg_att(const float* __restrict__ edge_attr,
                                                 const float* __restrict__ emb,
                                                 const int* __restrict__ offs,
                                                 const int* __restrict__ slots,
                                                 float* __restrict__ na) {
    int n = blockIdx.x * 4 + (threadIdx.x >> 6);
    int lane = threadIdx.x & 63;
    if (n >= NN) return;
    int s0 = offs[n], s1 = offs[n + 1];
    int deg = s1 - s0;
    float2 e = ((const float2*)(emb + (size_t)n * D))[lane];   // reused for every slot
    const float inv_scale = 0.08838834764831845f; // 1/sqrt(128)
    float2 acc = {0.f, 0.f};
    float wsum = 0.f;    // identical across lanes (post-butterfly w is wave-uniform)
    int base = 0;
    while (base < deg) {
        int chunk = deg - base;
        if (chunk > 64) chunk = 64;
        int sl = (lane < chunk) ? slots[s0 + base + lane] : 0;
        int j = 0;
        for (; j + 4 <= chunk; j += 4) {
            int r0 = __shfl(sl, j),     r1 = __shfl(sl, j + 1);
            int r2 = __shfl(sl, j + 2), r3 = __shfl(sl, j + 3);
            float2 a0 = ((const float2*)(edge_attr + (size_t)r0 * D))[lane];
            float2 a1 = ((const float2*)(edge_attr + (size_t)r1 * D))[lane];
            float2 a2 = ((const float2*)(edge_attr + (size_t)r2 * D))[lane];
            float2 a3 = ((const float2*)(edge_attr + (size_t)r3 * D))[lane];
            float d0 = a0.x * e.x + a0.y * e.y;
            float d1 = a1.x * e.x + a1.y * e.y;
            float d2 = a2.x * e.x + a2.y * e.y;
            float d3 = a3.x * e.x + a3.y * e.y;
            #pragma unroll
            for (int off = 32; off > 0; off >>= 1) {
                d0 += __shfl_xor(d0, off);
                d1 += __shfl_xor(d1, off);
                d2 += __shfl_xor(d2, off);
                d3 += __shfl_xor(d3, off);
            }
            float w0 = __expf(d0 * inv_scale);
            float w1 = __expf(d1 * inv_scale);
            float w2 = __expf(d2 * inv_scale);
            float w3 = __expf(d3 * inv_scale);
            acc.x += w0 * a0.x + w1 * a1.x + w2 * a2.x + w3 * a3.x;
            acc.y += w0 * a0.y + w1 * a1.y + w2 * a2.y + w3 * a3.y;
            wsum += (w0 + w1) + (w2 + w3);
        }
        for (; j < chunk; ++j) {
            int rr = __shfl(sl, j);
            float2 a = ((const float2*)(edge_attr + (size_t)rr * D))[lane];
            float d = a.x * e.x + a.y * e.y;
            #pragma unroll
            for (int off = 32; off > 0; off >>= 1) d += __shfl_xor(d, off);
            float w = __expf(d * inv_scale);
            acc.x += w * a.x;
            acc.y += w * a.y;
            wsum += w;
        }
        base += chunk;
    }
    float inv = (deg > 0) ? 1.f / wsum : 0.f;
    float2 r; r.x = acc.x * inv; r.y = acc.y * inv;
    ((float2*)(na + (size_t)n * D))[lane] = r;
}

// ===== scatter-mean: register-batched gathers, full wave per node =====
__global__ __launch_bounds__(256) void k_smean_gather(const float* __restrict__ cell_out,
                                                      const int* __restrict__ offs,
                                                      const int* __restrict__ slots,
                                                      float* __restrict__ node_out) {
    int n = blockIdx.x * 4 + (threadIdx.x >> 6);
    int lane = threadIdx.x & 63;
    if (n >= NN) return;
    int s0 = offs[n], s1 = offs[n + 1];
    int deg = s1 - s0;
    float2 acc = {0.f, 0.f};
    int base = 0;
    while (base < deg) {
        int chunk = deg - base;
        if (chunk > 64) chunk = 64;
        int sl = 0;
        if (lane < chunk) sl = slots[s0 + base + lane];
        int j = 0;
        for (; j + 4 <= chunk; j += 4) {
            int c0 = __shfl(sl, j),     c1 = __shfl(sl, j + 1);
            int c2 = __shfl(sl, j + 2), c3 = __shfl(sl, j + 3);
            float2 y0 = ((const float2*)(cell_out + (size_t)c0 * D))[lane];
            float2 y1 = ((const float2*)(cell_out + (size_t)c1 * D))[lane];
            float2 y2 = ((const float2*)(cell_out + (size_t)c2 * D))[lane];
            float2 y3 = ((const float2*)(cell_out + (size_t)c3 * D))[lane];
            acc.x += y0.x + y1.x + y2.x + y3.x;
            acc.y += y0.y + y1.y + y2.y + y3.y;
        }
        for (; j < chunk; ++j) {
            int cc = __shfl(sl, j);
            float2 y = ((const float2*)(cell_out + (size_t)cc * D))[lane];
            acc.x += y.x;
            acc.y += y.y;
        }
        base += chunk;
    }
    float inv = deg ? 1.f / (float)deg : 0.f;
    float2 r; r.x = acc.x * inv; r.y = acc.y * inv;
    ((float2*)(node_out + (size_t)n * D))[lane] = r;
}

// ================= fused gather + 2-layer MLP via bf16x3 MFMA =================
// Block: 32 cells, 256 threads = 4 waves. Wave w owns n-quarter [w*32, w*32+32)
// for BOTH 16-row tiles. X (32x256) staged in LDS as bf16 hi/lo with XOR swizzle.
__device__ __forceinline__ void stage_split(char* lds, int row, int col8, const float* v) {
    unsigned int byte = ((unsigned int)row << 9) + ((unsigned int)col8 << 4);
    byte ^= (unsigned int)(row & 7) << 4;            // G4 swizzle: kill stride-512B conflicts
    uint4 hi, lo;
    unsigned int* hp = (unsigned int*)&hi;
    unsigned int* lp = (unsigned int*)&lo;
    #pragma unroll
    for (int i = 0; i < 4; i++) {
        unsigned int h = cvt_pk_bf16(v[2 * i], v[2 * i + 1]);
        float h0 = __uint_as_float(h << 16);
        float h1 = __uint_as_float(h & 0xffff0000u);
        hp[i] = h;
        lp[i] = cvt_pk_bf16(v[2 * i] - h0, v[2 * i + 1] - h1);
    }
    *(uint4*)(lds + byte)         = hi;              // X-hi: [0, 16K)
    *(uint4*)(lds + 16384 + byte) = lo;              // X-lo: [16K, 32K)
}

__global__ __launch_bounds__(256, 5) void k_mlp(const float* __restrict__ cell_attr,
                                                const float* __restrict__ na,
                                                const int* __restrict__ face,
                                                const u16* __restrict__ w1h,
                                                const u16* __restrict__ w1l,
                                                const u16* __restrict__ w2h,
                                                const u16* __restrict__ w2l,
                                                const float* __restrict__ b1,
                                                const float* __restrict__ b2,
                                                float* __restrict__ out) {
    __shared__ char lds[32768];
    const int t  = threadIdx.x;
    const int c0 = blockIdx.x * 32;

    // ---- stage X = [cell_attr | mean-of-3-nodes] as bf16 hi/lo ----
    {
        const int r = t >> 3;        // 0..31  (cell row within tile)
        const int q = t & 7;         // 0..7   (16-col chunk)
        float v[16];
        const float* pa = cell_attr + (size_t)(c0 + r) * D + q * 16;
        #pragma unroll
        for (int i = 0; i < 4; i++) *(float4*)(v + 4 * i) = *(const float4*)(pa + 4 * i);
        stage_split(lds, r, q * 2,     v);
        stage_split(lds, r, q * 2 + 1, v + 8);

        const int cid = c0 + r;
        const int f0 = face[cid], f1 = face[NC + cid], f2 = face[2 * NC + cid];
        const float* p0 = na + (size_t)f0 * D + q * 16;
        const float* p1 = na + (size_t)f1 * D + q * 16;
        const float* p2 = na + (size_t)f2 * D + q * 16;
        const float third = 1.f / 3.f;
        #pragma unroll
        for (int i = 0; i < 4; i++) {
            float4 a0 = *(const float4*)(p0 + 4 * i);
            float4 a1 = *(const float4*)(p1 + 4 * i);
            float4 a2 = *(const float4*)(p2 + 4 * i);
            v[4 * i + 0] = (a0.x + a1.x + a2.x) * third;
            v[4 * i + 1] = (a0.y + a1.y + a2.y) * third;
            v[4 * i + 2] = (a0.z + a1.z + a2.z) * third;
            v[4 * i + 3] = (a0.w + a1.w + a2.w) * third;
        }
        stage_split(lds, r, 16 + q * 2, v);
        stage_split(lds, r, 17 + q * 2, v + 8);
    }
    __syncthreads();

    const int w  = t >> 6;           // wave 0..3 -> n-quarter
    const int l  = t & 63;
    const int lr = l & 15;           // A row / B-C col within tile
    const int lg = l >> 4;           // k group (8 contiguous k)
    const unsigned int swz = (unsigned int)(lr & 7) << 4;
    const size_t wl8 = (size_t)l * 8;
    const f32x4 z4 = {0.f, 0.f, 0.f, 0.f};
    f32x4 acc[2][2] = {{z4, z4}, {z4, z4}};          // [row-tile][n-tile]

    // ---- GEMM1: X (32x256) @ W1 (256x128), bf16x3 ----
    {
        const unsigned int abase = ((unsigned int)lr << 9) + ((unsigned int)lg << 4);
        const u16* pW1h = w1h + (size_t)(w * 2) * 512 + wl8;
        const u16* pW1l = w1l + (size_t)(w * 2) * 512 + wl8;
        #pragma unroll 2
        for (int kt = 0; kt < 8; ++kt) {
            unsigned int ab = (abase + (unsigned int)kt * 64) ^ swz;
            bf16x8 aH0 = *(const bf16x8*)(lds + ab);
            bf16x8 aL0 = *(const bf16x8*)(lds + 16384 + ab);
            bf16x8 aH1 = *(const bf16x8*)(lds + ab + 8192);          // rows 16..31
            bf16x8 aL1 = *(const bf16x8*)(lds + 16384 + ab + 8192);
            #pragma unroll
            for (int jn = 0; jn < 2; ++jn) {
                size_t fo = (size_t)(kt * 8 + jn) * 512;
                bf16x8 bH = *(const bf16x8*)(pW1h + fo);
                bf16x8 bL = *(const bf16x8*)(pW1l + fo);
                acc[0][jn] = MFMA16(aH0, bL, acc[0][jn]);
                acc[0][jn] = MFMA16(aL0, bH, acc[0][jn]);
                acc[0][jn] = MFMA16(aH0, bH, acc[0][jn]);
                acc[1][jn] = MFMA16(aH1, bL, acc[1][jn]);
                acc[1][jn] = MFMA16(aL1, bH, acc[1][jn]);
                acc[1][jn] = MFMA16(aH1, bH, acc[1][jn]);
            }
        }
    }

    __syncthreads();   // all waves done reading X before H overwrites it

    // ---- bias + relu, re-split H (32x128) into LDS (reuses X-hi region) ----
    {
        const int col0 = w * 32 + lr;          // jn = 0
        const int col1 = col0 + 16;            // jn = 1
        const float bb0 = b1[col0];
        const float bb1 = b1[col1];
        #pragma unroll
        for (int rt = 0; rt < 2; ++rt) {
            #pragma unroll
            for (int r = 0; r < 4; ++r) {
                int row = rt * 16 + lg * 4 + r;       // C/D: row = 4*(lane>>4)+reg
                float h0 = fmaxf(acc[rt][0][r] + bb0, 0.f);
                float h1 = fmaxf(acc[rt][1][r] + bb1, 0.f);
                unsigned int ph = cvt_pk_bf16(h0, h1);
                float f0 = __uint_as_float(ph << 16);
                float f1 = __uint_as_float(ph & 0xffff0000u);
                unsigned int pl = cvt_pk_bf16(h0 - f0, h1 - f1);
                unsigned int swzr = (unsigned int)(row & 7) << 4;
                unsigned int b0 = (((unsigned int)row << 8) + ((unsigned int)col0 << 1)) ^ swzr;
                unsigned int bcol1 = (((unsigned int)row << 8) + ((unsigned int)col1 << 1)) ^ swzr;
                *(u16*)(lds + b0)            = (u16)ph;       // H-hi: [0, 8K)
                *(u16*)(lds + bcol1)         = (u16)(ph >> 16);
                *(u16*)(lds + 8192 + b0)     = (u16)pl;       // H-lo: [8K, 16K)
                *(u16*)(lds + 8192 + bcol1)  = (u16)(pl >> 16);
            }
        }
    }
    __syncthreads();

    // ---- GEMM2: H (32x128) @ W2 (128x128), bf16x3 ----
    f32x4 acc2[2][2] = {{z4, z4}, {z4, z4}};
    {
        const unsigned int abase = ((unsigned int)lr << 8) + ((unsigned int)lg << 4);
        const u16* pW2h = w2h + (size_t)(w * 2) * 512 + wl8;
        const u16* pW2l = w2l + (size_t)(w * 2) * 512 + wl8;
        #pragma unroll 2
        for (int kt = 0; kt < 4; ++kt) {
            unsigned int ab = (abase + (unsigned int)kt * 64) ^ swz;
            bf16x8 aH0 = *(const bf16x8*)(lds + ab);
            bf16x8 aL0 = *(const bf16x8*)(lds + 8192 + ab);
            bf16x8 aH1 = *(const bf16x8*)(lds + ab + 4096);          // rows 16..31
            bf16x8 aL1 = *(const bf16x8*)(lds + 8192 + ab + 4096);
            #pragma unroll
            for (int jn = 0; jn < 2; ++jn) {
                size_t fo = (size_t)(kt * 8 + jn) * 512;
                bf16x8 bH = *(const bf16x8*)(pW2h + fo);
                bf16x8 bL = *(const bf16x8*)(pW2l + fo);
                acc2[0][jn] = MFMA16(aH0, bL, acc2[0][jn]);
                acc2[0][jn] = MFMA16(aL0, bH, acc2[0][jn]);
                acc2[0][jn] = MFMA16(aH0, bH, acc2[0][jn]);
                acc2[1][jn] = MFMA16(aH1, bL, acc2[1][jn]);
                acc2[1][jn] = MFMA16(aL1, bH, acc2[1][jn]);
                acc2[1][jn] = MFMA16(aH1, bH, acc2[1][jn]);
            }
        }
    }

    // ---- bias + store ----
    #pragma unroll
    for (int jn = 0; jn < 2; ++jn) {
        int col = w * 32 + jn * 16 + lr;
        float bb = b2[col];
        #pragma unroll
        for (int rt = 0; rt < 2; ++rt) {
            #pragma unroll
            for (int r = 0; r < 4; ++r) {
                int row = c0 + rt * 16 + lg * 4 + r;
                out[(size_t)row * D + col] = acc2[rt][jn][r] + bb;
            }
        }
    }
}

extern "C" void kernel_launch(void* const* d_in, const int* in_sizes, int n_in,
                              void* d_out, int out_size, void* d_ws, size_t ws_size,
                              hipStream_t stream) {
    (void)in_sizes; (void)n_in; (void)out_size; (void)ws_size;
    const float* cell_attr = (const float*)d_in[0];
    const float* edge_attr = (const float*)d_in[1];
    const float* emb       = (const float*)d_in[2];
    const int*   ei        = (const int*)d_in[3];
    const int*   face      = (const int*)d_in[4];
    const float* W1        = (const float*)d_in[5];
    const float* b1        = (const float*)d_in[6];
    const float* W2        = (const float*)d_in[7];
    const float* b2        = (const float*)d_in[8];

    float* out_cell = (float*)d_out;                    // [C*D]
    float* out_node = out_cell + (size_t)NC * D;        // [N*D] (node_agg scratch, then final)

    // ws layout (4B units) — zeroed arrays first
    int*   cntA   = (int*)d_ws;                   // [N]
    int*   cntF   = cntA + NN;                    // [N]
    int*   curA   = cntF + NN;                    // [N]
    int*   curF   = curA + NN;                    // [N]
    int*   offA   = curF + NN;                    // [N+1]
    int*   offF   = offA + NN + 1;                // [N+1]
    int*   bsumA  = offF + NN + 1;                // [512]
    int*   bsumF  = bsumA + 512;                  // [512]
    int*   slotsA = bsumF + 512;                  // [2E]
    int*   slotsF = slotsA + 2 * NE;              // [3C]
    // W fragment arrays (16B-aligned): 192 KB
    u16* w1h = (u16*)(((uintptr_t)(slotsF + 3 * NC) + 15) & ~(uintptr_t)15);
    u16* w1l = w1h + 64 * 512;
    u16* w2h = w1l + 64 * 512;                    // 32 frags * 512 u16
    u16* w2l = w2h + 32 * 512;

    hipMemsetAsync(d_ws, 0, (size_t)4 * NN * 4, stream);   // cntA, cntF, curA, curF

    k_hist_w<<<2 * HB + 24, 256, 0, stream>>>(ei, face, cntA, cntF, W1, W2,
                                              w1h, w1l, w2h, w2l);

    k_scan_blocks<<<2 * NB, 256, 0, stream>>>(cntA, cntF, bsumA, bsumF);
    k_scan_top   <<<2, 512, 0, stream>>>(bsumA, bsumF, NB);
    k_scan_final <<<2 * NB, 256, 0, stream>>>(cntA, cntF, bsumA, bsumF, offA, offF);

    k_fill<<<2 * HB, 256, 0, stream>>>(ei, face, offA, offF, curA, curF, slotsA, slotsF);

    k_agg_att<<<(NN + 3) / 4, 256, 0, stream>>>(edge_attr, emb, offA, slotsA, out_node);

    k_mlp<<<NC / 32, 256, 0, stream>>>(cell_attr, out_node, face,
                                       w1h, w1l, w2h, w2l, b1, b2, out_cell);

    k_smean_gather<<<(NN + 3) / 4, 256, 0, stream>>>(out_cell, offF, slotsF, out_node);
}